// Round 3
// baseline (1474.608 us; speedup 1.0000x reference)
//
#include <hip/hip_runtime.h>
#include <hip/hip_bf16.h>
#include <math.h>

typedef __hip_bfloat16 bf16;

#define NT 2
#define NE 2
#define NN 50000
#define FIN 128
#define HID 128
#define NH 4
#define DD 32
#define NL 2
#define NEDGE 400000
#define NCHUNK 196   // ceil(50000/256)

__device__ __forceinline__ float b2f(bf16 v) { return __bfloat162float(v); }
__device__ __forceinline__ bf16 f2b(float v) { return __float2bfloat16(v); }
__device__ __forceinline__ float sigm(float x) { return 1.0f / (1.0f + __expf(-x)); }
__device__ __forceinline__ float toF(float v) { return v; }
__device__ __forceinline__ float toF(bf16 v) { return b2f(v); }

// ---- input dtype detection --------------------------------------------------
// bf16 N(0,1) data: nearly all u16 words have exponent-field in [110,135].
// fp32 data: only the high half-words do (~55% hits). Threshold at 200/256.
__global__ void detect_kernel(const void* __restrict__ x, int* __restrict__ flag) {
    int lane = threadIdx.x;  // 64
    const unsigned short* u = (const unsigned short*)x;
    int cnt = 0;
    for (int i = 0; i < 4; i++) {
        unsigned short w = u[lane * 4 + i];
        int e = (w >> 7) & 0xFF;
        if (e >= 110 && e <= 135) cnt++;
    }
    for (int off = 32; off > 0; off >>= 1) cnt += __shfl_xor(cnt, off, 64);
    if (lane == 0) *flag = (cnt > 200) ? 0 : 1;   // 0 = bf16, 1 = fp32
}

// ---- edge-weight "last write wins" index ------------------------------------
__global__ void lastmax_kernel(const int* __restrict__ ei, int* __restrict__ lastidx) {
    int idx = blockIdx.x * blockDim.x + threadIdx.x;
    if (idx >= NE * NEDGE) return;
    int e = idx / NEDGE, j = idx % NEDGE;
    int src = ei[(e * 2 + 0) * NEDGE + j];   // EDGE_SRC = (0,1): src type == e
    atomicMax(&lastidx[e * NN + src], j);
}

// ---- CSR build --------------------------------------------------------------
__global__ void count_kernel(const int* __restrict__ ei, int* __restrict__ counts) {
    int idx = blockIdx.x * blockDim.x + threadIdx.x;
    if (idx >= NE * NEDGE) return;
    int e = idx / NEDGE, j = idx % NEDGE;
    int dst = ei[(e * 2 + 1) * NEDGE + j];
    atomicAdd(&counts[e * NN + dst], 1);
}

__global__ void scan1_kernel(const int* __restrict__ counts, int* __restrict__ offs,
                             int* __restrict__ bsum) {
    int e = blockIdx.x / NCHUNK, cb = blockIdx.x % NCHUNK;
    int tid = threadIdx.x;
    int idx = cb * 256 + tid;
    int v = (idx < NN) ? counts[e * NN + idx] : 0;
    __shared__ int sb[256];
    sb[tid] = v; __syncthreads();
    for (int off = 1; off < 256; off <<= 1) {
        int a = (tid >= off) ? sb[tid - off] : 0;
        __syncthreads();
        sb[tid] += a;
        __syncthreads();
    }
    if (idx < NN) offs[e * (NN + 1) + idx] = sb[tid] - v;
    if (tid == 255) bsum[e * NCHUNK + cb] = sb[255];
}

__global__ void scan2_kernel(int* __restrict__ bsum) {
    int e = blockIdx.x;
    int tid = threadIdx.x;
    int v = (tid < NCHUNK) ? bsum[e * NCHUNK + tid] : 0;
    __shared__ int sb[256];
    sb[tid] = v; __syncthreads();
    for (int off = 1; off < 256; off <<= 1) {
        int a = (tid >= off) ? sb[tid - off] : 0;
        __syncthreads();
        sb[tid] += a;
        __syncthreads();
    }
    if (tid < NCHUNK) bsum[e * NCHUNK + tid] = sb[tid] - v;
}

__global__ void scan3_kernel(int* __restrict__ offs, const int* __restrict__ bsum,
                             int* __restrict__ cursor) {
    int e = blockIdx.x / NCHUNK, cb = blockIdx.x % NCHUNK;
    int idx = cb * 256 + threadIdx.x;
    if (idx < NN) {
        int v = offs[e * (NN + 1) + idx] + bsum[e * NCHUNK + cb];
        offs[e * (NN + 1) + idx] = v;
        cursor[e * NN + idx] = v;
    } else if (idx == NN) {
        offs[e * (NN + 1) + NN] = NEDGE;
    }
}

__global__ void fill_kernel(const int* __restrict__ ei, int* __restrict__ cursor,
                            int* __restrict__ bucket) {
    int idx = blockIdx.x * blockDim.x + threadIdx.x;
    if (idx >= NE * NEDGE) return;
    int e = idx / NEDGE, j = idx % NEDGE;
    int dst = ei[(e * 2 + 1) * NEDGE + j];
    int pos = atomicAdd(&cursor[e * NN + dst], 1);
    bucket[e * NEDGE + pos] = j;
}

// ---- input projection + ReLU + last-edge sigmoid scale ----------------------
template <typename T>
__device__ __forceinline__ void lin_body(const T* __restrict__ x, const T* __restrict__ lin_w,
                                         const T* __restrict__ lin_b, const int* __restrict__ lastidx,
                                         const T* __restrict__ ew, float* __restrict__ h) {
    int blk = blockIdx.x;
    int t = blk / (NN / 4);
    int n0 = (blk % (NN / 4)) * 4;
    int tid = threadIdx.x;              // 128
    __shared__ float rows[4][FIN];
    for (int r = 0; r < 4; r++)
        rows[r][tid] = toF(x[((size_t)(t * NN + n0 + r)) * FIN + tid]);
    __syncthreads();
    const T* W = lin_w + (size_t)t * FIN * HID;
    float bias = toF(lin_b[t * HID + tid]);
    float acc0 = bias, acc1 = bias, acc2 = bias, acc3 = bias;
#pragma unroll 8
    for (int k = 0; k < FIN; k++) {
        float w = toF(W[k * HID + tid]);
        acc0 += rows[0][k] * w;
        acc1 += rows[1][k] * w;
        acc2 += rows[2][k] * w;
        acc3 += rows[3][k] * w;
    }
    float acc[4] = {acc0, acc1, acc2, acc3};
    for (int r = 0; r < 4; r++) {
        int n = n0 + r;
        float v = fmaxf(acc[r], 0.0f);
        int li = lastidx[t * NN + n];
        if (li >= 0 && li < NEDGE) v *= sigm(toF(ew[t * NEDGE + li]));
        h[((size_t)(t * NN + n)) * HID + tid] = v;
    }
}

__global__ void lin_kernel(const void* x, const void* lin_w, const void* lin_b,
                           const int* lastidx, const void* ew, float* h, const int* flag) {
    if (*flag) lin_body<float>((const float*)x, (const float*)lin_w, (const float*)lin_b,
                               lastidx, (const float*)ew, h);
    else       lin_body<bf16>((const bf16*)x, (const bf16*)lin_w, (const bf16*)lin_b,
                              lastidx, (const bf16*)ew, h);
}

// ---- fused K/Q/V projection (k,v -> bf16 internal; q -> fp32) ---------------
template <typename T>
__device__ __forceinline__ void kqv_body(const float* __restrict__ h,
                                         const T* __restrict__ kw, const T* __restrict__ qw,
                                         const T* __restrict__ vw,
                                         const T* __restrict__ kb, const T* __restrict__ qb,
                                         const T* __restrict__ vb, int l,
                                         bf16* __restrict__ ko, float* __restrict__ qo,
                                         bf16* __restrict__ vo) {
    int blk = blockIdx.x;
    int t = blk / (NN / 4);
    int n0 = (blk % (NN / 4)) * 4;
    int tid = threadIdx.x;
    __shared__ float rows[4][HID];
    for (int r = 0; r < 4; r++)
        rows[r][tid] = h[((size_t)(t * NN + n0 + r)) * HID + tid];
    __syncthreads();
    size_t wb = ((size_t)l * NT + t) * HID * HID;
    size_t bb = ((size_t)l * NT + t) * HID;
    const T* Wk = kw + wb;
    const T* Wq = qw + wb;
    const T* Wv = vw + wb;
    float ak0 = toF(kb[bb + tid]), ak1 = ak0, ak2 = ak0, ak3 = ak0;
    float aq0 = toF(qb[bb + tid]), aq1 = aq0, aq2 = aq0, aq3 = aq0;
    float av0 = toF(vb[bb + tid]), av1 = av0, av2 = av0, av3 = av0;
#pragma unroll 4
    for (int k = 0; k < HID; k++) {
        float wk = toF(Wk[k * HID + tid]);
        float wq = toF(Wq[k * HID + tid]);
        float wv = toF(Wv[k * HID + tid]);
        float r0 = rows[0][k], r1 = rows[1][k], r2 = rows[2][k], r3 = rows[3][k];
        ak0 += r0 * wk; ak1 += r1 * wk; ak2 += r2 * wk; ak3 += r3 * wk;
        aq0 += r0 * wq; aq1 += r1 * wq; aq2 += r2 * wq; aq3 += r3 * wq;
        av0 += r0 * wv; av1 += r1 * wv; av2 += r2 * wv; av3 += r3 * wv;
    }
    size_t b = ((size_t)(t * NN + n0)) * HID + tid;
    ko[b] = f2b(ak0); ko[b + HID] = f2b(ak1); ko[b + 2 * HID] = f2b(ak2); ko[b + 3 * HID] = f2b(ak3);
    qo[b] = aq0; qo[b + HID] = aq1; qo[b + 2 * HID] = aq2; qo[b + 3 * HID] = aq3;
    vo[b] = f2b(av0); vo[b + HID] = f2b(av1); vo[b + 2 * HID] = f2b(av2); vo[b + 3 * HID] = f2b(av3);
}

__global__ void kqv_kernel(const float* h, const void* kw, const void* qw, const void* vw,
                           const void* kb, const void* qb, const void* vb, int l,
                           bf16* ko, float* qo, bf16* vo, const int* flag) {
    if (*flag) kqv_body<float>(h, (const float*)kw, (const float*)qw, (const float*)vw,
                               (const float*)kb, (const float*)qb, (const float*)vb, l, ko, qo, vo);
    else       kqv_body<bf16>(h, (const bf16*)kw, (const bf16*)qw, (const bf16*)vw,
                              (const bf16*)kb, (const bf16*)qb, (const bf16*)vb, l, ko, qo, vo);
}

// ---- per-head D x D relation transform (in-place over bf16 k/v rows) --------
template <typename T>
__device__ __forceinline__ void rel_body(bf16* __restrict__ kin, bf16* __restrict__ vin,
                                         const T* __restrict__ A, const T* __restrict__ M, int le) {
    int n = blockIdx.x;
    int tid = threadIdx.x;          // 128 = 4 heads x 32
    int hh = tid >> 5, dd = tid & 31;
    __shared__ float kk[HID], vv[HID];
    kk[tid] = b2f(kin[(size_t)n * HID + tid]);
    vv[tid] = b2f(vin[(size_t)n * HID + tid]);
    __syncthreads();
    const T* Ah = A + ((size_t)le * NH + hh) * DD * DD;
    const T* Mh = M + ((size_t)le * NH + hh) * DD * DD;
    float ka = 0.0f, va = 0.0f;
#pragma unroll 8
    for (int d = 0; d < DD; d++) {
        float kv = kk[hh * DD + d];
        float vw = vv[hh * DD + d];
        ka += kv * toF(Ah[d * DD + dd]);
        va += vw * toF(Mh[d * DD + dd]);
    }
    kin[(size_t)n * HID + tid] = f2b(ka);
    vin[(size_t)n * HID + tid] = f2b(va);
}

__global__ void rel_kernel(bf16* kin, bf16* vin, const void* A, const void* M,
                           int le, const int* flag) {
    if (*flag) rel_body<float>(kin, vin, (const float*)A, (const float*)M, le);
    else       rel_body<bf16>(kin, vin, (const bf16*)A, (const bf16*)M, le);
}

// ---- per-dst-node online-softmax aggregation --------------------------------
// agg_t may alias q_t (each thread reads its q element once before any write;
// blocks touch disjoint dst rows).
template <typename T>
__device__ __forceinline__ void agg_body(const float* __restrict__ q_t, const bf16* __restrict__ k_rel,
                                         const bf16* __restrict__ v_rel, const int* __restrict__ ei_src,
                                         const int* __restrict__ bucket_e, const int* __restrict__ offs_e,
                                         const T* __restrict__ rel_p, int le, float* __restrict__ agg_t) {
    int dst = blockIdx.x;
    int tid = threadIdx.x;          // 128 = 4 heads x 32
    int hh = tid >> 5;
    int beg = offs_e[dst], end = offs_e[dst + 1];
    size_t obase = (size_t)dst * HID + tid;
    if (beg == end) { agg_t[obase] = 0.0f; return; }
    float qv = q_t[obase];
    float scale = toF(rel_p[(size_t)le * NH + hh]) * 0.17677669529663687f;  // 1/sqrt(32)
    float m = -3.0e38f, l = 0.0f, acc = 0.0f;
    for (int j = beg; j < end; j++) {
        int eid = bucket_e[j];
        int src = ei_src[eid];
        float p = qv * b2f(k_rel[(size_t)src * HID + tid]);
        for (int off = 16; off > 0; off >>= 1) p += __shfl_xor(p, off, 64);
        float s = p * scale;
        float mn = fmaxf(m, s);
        float es = __expf(s - mn);
        float sc = __expf(m - mn);    // first iter: exp(-huge) = 0
        l = l * sc + es;
        acc = acc * sc + es * b2f(v_rel[(size_t)src * HID + tid]);
        m = mn;
    }
    agg_t[obase] = acc / (l + 1e-16f);
}

__global__ void agg_kernel(const float* q_t, const bf16* k_rel, const bf16* v_rel,
                           const int* ei_src, const int* bucket_e, const int* offs_e,
                           const void* rel_p, int le, float* agg_t, const int* flag) {
    if (*flag) agg_body<float>(q_t, k_rel, v_rel, ei_src, bucket_e, offs_e,
                               (const float*)rel_p, le, agg_t);
    else       agg_body<bf16>(q_t, k_rel, v_rel, ei_src, bucket_e, offs_e,
                              (const bf16*)rel_p, le, agg_t);
}

// ---- GELU + output projection + gated residual ------------------------------
template <typename T>
__device__ __forceinline__ void outproj_body(const float* __restrict__ agg, const T* __restrict__ aw,
                                             const T* __restrict__ ab, const T* __restrict__ skip,
                                             int l, float* __restrict__ h) {
    int blk = blockIdx.x;
    int t = blk / (NN / 4);
    int n0 = (blk % (NN / 4)) * 4;
    int tid = threadIdx.x;
    __shared__ float rows[4][HID];
    for (int r = 0; r < 4; r++) {
        float g = agg[((size_t)(t * NN + n0 + r)) * HID + tid];
        rows[r][tid] = 0.5f * g * (1.0f + erff(g * 0.70710678118654752f));  // exact gelu
    }
    __syncthreads();
    const T* W = aw + ((size_t)l * NT + t) * HID * HID;
    float bias = toF(ab[((size_t)l * NT + t) * HID + tid]);
    float acc0 = bias, acc1 = bias, acc2 = bias, acc3 = bias;
#pragma unroll 8
    for (int k = 0; k < HID; k++) {
        float w = toF(W[k * HID + tid]);
        acc0 += rows[0][k] * w;
        acc1 += rows[1][k] * w;
        acc2 += rows[2][k] * w;
        acc3 += rows[3][k] * w;
    }
    float beta = sigm(toF(skip[l * NT + t]));
    float acc[4] = {acc0, acc1, acc2, acc3};
    for (int r = 0; r < 4; r++) {
        size_t i = ((size_t)(t * NN + n0 + r)) * HID + tid;
        h[i] = beta * acc[r] + (1.0f - beta) * h[i];
    }
}

__global__ void outproj_kernel(const float* agg, const void* aw, const void* ab,
                               const void* skip, int l, float* h, const int* flag) {
    if (*flag) outproj_body<float>(agg, (const float*)aw, (const float*)ab,
                                   (const float*)skip, l, h);
    else       outproj_body<bf16>(agg, (const bf16*)aw, (const bf16*)ab,
                                  (const bf16*)skip, l, h);
}

__global__ void store_out_kernel(const float* __restrict__ h, void* __restrict__ out,
                                 const int* __restrict__ flag) {
    int idx = blockIdx.x * blockDim.x + threadIdx.x;
    if (idx >= NT * NN * HID) return;
    if (*flag) ((float*)out)[idx] = h[idx];
    else       ((bf16*)out)[idx] = f2b(h[idx]);
}

extern "C" void kernel_launch(void* const* d_in, const int* in_sizes, int n_in,
                              void* d_out, int out_size, void* d_ws, size_t ws_size,
                              hipStream_t stream) {
    const void* x      = d_in[0];
    const int*  ei     = (const int*)d_in[1];
    const void* ew     = d_in[2];
    const void* lin_w  = d_in[3];
    const void* lin_b  = d_in[4];
    const void* k_w    = d_in[5];
    const void* k_b    = d_in[6];
    const void* q_w    = d_in[7];
    const void* q_b    = d_in[8];
    const void* v_w    = d_in[9];
    const void* v_b    = d_in[10];
    const void* a_w    = d_in[11];
    const void* a_b    = d_in[12];
    const void* skip   = d_in[13];
    const void* rel_att = d_in[14];
    const void* rel_msg = d_in[15];
    const void* rel_p  = d_in[16];

    char* p = (char*)d_ws;
    auto alloc = [&](size_t bytes) -> char* {
        char* r = p;
        p += (bytes + 255) & ~(size_t)255;
        return r;
    };
    int* flag     = (int*)alloc(sizeof(int));
    int* counts   = (int*)alloc(sizeof(int) * NE * NN);
    int* offs     = (int*)alloc(sizeof(int) * NE * (NN + 1));
    int* bsum     = (int*)alloc(sizeof(int) * NE * NCHUNK);
    int* cursor   = (int*)alloc(sizeof(int) * NE * NN);
    int* bucket   = (int*)alloc(sizeof(int) * NE * NEDGE);
    int* lastidx  = (int*)alloc(sizeof(int) * NT * NN);
    float* h      = (float*)alloc(sizeof(float) * NT * NN * HID);   // 51.2 MB
    float* qq     = (float*)alloc(sizeof(float) * NT * NN * HID);   // 51.2 MB (agg aliases)
    bf16*  kk     = (bf16*)alloc(sizeof(bf16) * NT * NN * HID);     // 25.6 MB
    bf16*  vv     = (bf16*)alloc(sizeof(bf16) * NT * NN * HID);     // 25.6 MB
    float* agg    = qq;

    hipMemsetAsync(lastidx, 0xFF, sizeof(int) * NT * NN, stream);   // -1
    hipMemsetAsync(counts, 0, sizeof(int) * NE * NN, stream);

    detect_kernel<<<1, 64, 0, stream>>>(x, flag);
    lastmax_kernel<<<(NE * NEDGE + 255) / 256, 256, 0, stream>>>(ei, lastidx);
    count_kernel<<<(NE * NEDGE + 255) / 256, 256, 0, stream>>>(ei, counts);
    lin_kernel<<<NT * NN / 4, 128, 0, stream>>>(x, lin_w, lin_b, lastidx, ew, h, flag);
    scan1_kernel<<<NE * NCHUNK, 256, 0, stream>>>(counts, offs, bsum);
    scan2_kernel<<<NE, 256, 0, stream>>>(bsum);
    scan3_kernel<<<NE * NCHUNK, 256, 0, stream>>>(offs, bsum, cursor);
    fill_kernel<<<(NE * NEDGE + 255) / 256, 256, 0, stream>>>(ei, cursor, bucket);

    const int EDGE_SRC_[NE] = {0, 1};
    const int EDGE_DST_[NE] = {1, 0};
    for (int l = 0; l < NL; l++) {
        kqv_kernel<<<NT * NN / 4, 128, 0, stream>>>(h, k_w, q_w, v_w, k_b, q_b, v_b, l,
                                                    kk, qq, vv, flag);
        for (int e = 0; e < NE; e++) {
            int s = EDGE_SRC_[e], t = EDGE_DST_[e];
            int le = l * NE + e;
            rel_kernel<<<NN, 128, 0, stream>>>(
                kk + (size_t)s * NN * HID, vv + (size_t)s * NN * HID,
                rel_att, rel_msg, le, flag);
            agg_kernel<<<NN, 128, 0, stream>>>(
                qq + (size_t)t * NN * HID,
                kk + (size_t)s * NN * HID, vv + (size_t)s * NN * HID,
                ei + (e * 2 + 0) * NEDGE, bucket + (size_t)e * NEDGE,
                offs + (size_t)e * (NN + 1),
                rel_p, le, agg + (size_t)t * NN * HID, flag);
        }
        outproj_kernel<<<NT * NN / 4, 128, 0, stream>>>(agg, a_w, a_b, skip, l, h, flag);
    }
    store_out_kernel<<<(NT * NN * HID + 255) / 256, 256, 0, stream>>>(h, d_out, flag);
}

// Round 4
// 665.508 us; speedup vs baseline: 2.2158x; 2.2158x over previous
//
#include <hip/hip_runtime.h>
#include <hip/hip_bf16.h>
#include <math.h>

typedef __hip_bfloat16 bf16;
typedef __attribute__((ext_vector_type(8))) short bf16x8;   // 8 bf16 = 4 VGPRs (MFMA A/B frag)
typedef __attribute__((ext_vector_type(4))) float f32x4;    // MFMA C/D frag

#define NT 2
#define NE 2
#define NN 50000
#define HID 128
#define NH 4
#define DD 32
#define NL 2
#define NEDGE 400000
#define NCHUNK 196      // ceil(50000/256)
#define MBLK 391        // ceil(50000/128)
#define LDSPITCH 136    // 128 + 8 bf16 pad -> row stride 272 B (16B-aligned, 2-way banks = free)

__device__ __forceinline__ float b2f(bf16 v) { return __bfloat162float(v); }
__device__ __forceinline__ float toF(float v) { return v; }
__device__ __forceinline__ float toF(bf16 v) { return b2f(v); }
__device__ __forceinline__ float sigm(float x) { return 1.0f / (1.0f + __expf(-x)); }
__device__ __forceinline__ unsigned short f2bits(float f) {
    bf16 h = __float2bfloat16(f);
    unsigned short b; __builtin_memcpy(&b, &h, 2); return b;
}
__device__ __forceinline__ float bits2f(unsigned short b) {
    unsigned u = ((unsigned)b) << 16; float f; __builtin_memcpy(&f, &u, 4); return f;
}

// ---- input dtype detection (0 = bf16, 1 = fp32) -----------------------------
__global__ void detect_kernel(const void* __restrict__ x, int* __restrict__ flag) {
    int lane = threadIdx.x;  // 64
    const unsigned short* u = (const unsigned short*)x;
    int cnt = 0;
    for (int i = 0; i < 4; i++) {
        unsigned short w = u[lane * 4 + i];
        int e = (w >> 7) & 0xFF;
        if (e >= 110 && e <= 135) cnt++;
    }
    for (int off = 32; off > 0; off >>= 1) cnt += __shfl_xor(cnt, off, 64);
    if (lane == 0) *flag = (cnt > 200) ? 0 : 1;
}

// ---- merged last-edge-index + dst-degree count ------------------------------
__global__ void lastcnt_kernel(const int* __restrict__ ei, int* __restrict__ lastidx,
                               int* __restrict__ counts) {
    int idx = blockIdx.x * blockDim.x + threadIdx.x;
    if (idx >= NE * NEDGE) return;
    int e = idx / NEDGE, j = idx % NEDGE;
    int src = ei[(e * 2 + 0) * NEDGE + j];   // EDGE_SRC=(0,1): src type == e
    int dst = ei[(e * 2 + 1) * NEDGE + j];
    atomicMax(&lastidx[e * NN + src], j);
    atomicAdd(&counts[e * NN + dst], 1);
}

// ---- CSR scans --------------------------------------------------------------
__global__ void scan1_kernel(const int* __restrict__ counts, int* __restrict__ offs,
                             int* __restrict__ bsum) {
    int e = blockIdx.x / NCHUNK, cb = blockIdx.x % NCHUNK;
    int tid = threadIdx.x;
    int idx = cb * 256 + tid;
    int v = (idx < NN) ? counts[e * NN + idx] : 0;
    __shared__ int sb[256];
    sb[tid] = v; __syncthreads();
    for (int off = 1; off < 256; off <<= 1) {
        int a = (tid >= off) ? sb[tid - off] : 0;
        __syncthreads();
        sb[tid] += a;
        __syncthreads();
    }
    if (idx < NN) offs[e * (NN + 1) + idx] = sb[tid] - v;
    if (tid == 255) bsum[e * NCHUNK + cb] = sb[255];
}

__global__ void scan2_kernel(int* __restrict__ bsum) {
    int e = blockIdx.x;
    int tid = threadIdx.x;
    int v = (tid < NCHUNK) ? bsum[e * NCHUNK + tid] : 0;
    __shared__ int sb[256];
    sb[tid] = v; __syncthreads();
    for (int off = 1; off < 256; off <<= 1) {
        int a = (tid >= off) ? sb[tid - off] : 0;
        __syncthreads();
        sb[tid] += a;
        __syncthreads();
    }
    if (tid < NCHUNK) bsum[e * NCHUNK + tid] = sb[tid] - v;
}

__global__ void scan3_kernel(int* __restrict__ offs, const int* __restrict__ bsum,
                             int* __restrict__ cursor) {
    int e = blockIdx.x / NCHUNK, cb = blockIdx.x % NCHUNK;
    int idx = cb * 256 + threadIdx.x;
    if (idx < NN) {
        int v = offs[e * (NN + 1) + idx] + bsum[e * NCHUNK + cb];
        offs[e * (NN + 1) + idx] = v;
        cursor[e * NN + idx] = v;
    } else if (idx == NN) {
        offs[e * (NN + 1) + NN] = NEDGE;
    }
}

// ---- CSR fill: store SRC node directly (skip edge-id indirection) -----------
__global__ void fill_kernel(const int* __restrict__ ei, int* __restrict__ cursor,
                            int* __restrict__ srcb) {
    int idx = blockIdx.x * blockDim.x + threadIdx.x;
    if (idx >= NE * NEDGE) return;
    int e = idx / NEDGE, j = idx % NEDGE;
    int src = ei[(e * 2 + 0) * NEDGE + j];
    int dst = ei[(e * 2 + 1) * NEDGE + j];
    int pos = atomicAdd(&cursor[e * NN + dst], 1);
    srcb[e * NEDGE + pos] = src;
}

// ---- per-node sigmoid(ew[last]) scale ---------------------------------------
template <typename T>
__device__ __forceinline__ void ewsc_body(const T* __restrict__ ew, const int* __restrict__ lastidx,
                                          float* __restrict__ ewsc) {
    int idx = blockIdx.x * blockDim.x + threadIdx.x;
    if (idx >= NT * NN) return;
    int t = idx / NN;
    int li = lastidx[idx];
    ewsc[idx] = (li >= 0) ? sigm(toF(ew[(size_t)t * NEDGE + li])) : 1.0f;
}
__global__ void ewsc_kernel(const void* ew, const int* lastidx, float* ewsc, const int* flag) {
    if (*flag) ewsc_body<float>((const float*)ew, lastidx, ewsc);
    else       ewsc_body<bf16>((const bf16*)ew, lastidx, ewsc);
}

// ---- weight prep: transpose + fold rel into K/V weights ---------------------
// wT layout (bf16, [n][k] each): mat 0,1 = linT[t]; mat 2+lt*3+{0,1,2} = kT_fold,qT,vT_fold
// (lt = l*2+t); mat 14+lt = aT.
template <typename T>
__device__ __forceinline__ void prep_w_body(const T* lin_w, const T* k_w, const T* q_w,
                                            const T* v_w, const T* a_w, const T* rel_att,
                                            const T* rel_msg, unsigned short* wT) {
    int bid = blockIdx.x, tid = threadIdx.x;
    int mat = bid >> 6;
    int elem = (bid & 63) * 256 + tid;
    int n = elem >> 7, k = elem & 127;
    float v;
    if (mat < 2) {
        v = toF(lin_w[(size_t)mat * 16384 + k * 128 + n]);
    } else if (mat < 14) {
        int m2 = mat - 2, lt = m2 / 3, op = m2 % 3;
        if (op == 1) {
            v = toF(q_w[(size_t)lt * 16384 + k * 128 + n]);
        } else {
            const T* w = (op == 0 ? k_w : v_w) + (size_t)lt * 16384 + k * 128;
            const T* rl = (op == 0 ? rel_att : rel_msg) + (size_t)lt * 4096;  // e == t
            int hh = n >> 5, jj = n & 31;
            float s = 0.f;
#pragma unroll 8
            for (int d = 0; d < 32; d++)
                s += toF(w[hh * 32 + d]) * toF(rl[(hh * 32 + d) * 32 + jj]);
            v = s;
        }
    } else {
        v = toF(a_w[(size_t)(mat - 14) * 16384 + k * 128 + n]);
    }
    wT[(size_t)mat * 16384 + n * 128 + k] = f2bits(v);
}
__global__ void prep_w_kernel(const void* lin_w, const void* k_w, const void* q_w,
                              const void* v_w, const void* a_w, const void* rel_att,
                              const void* rel_msg, unsigned short* wT, const int* flag) {
    if (*flag) prep_w_body<float>((const float*)lin_w, (const float*)k_w, (const float*)q_w,
                                  (const float*)v_w, (const float*)a_w, (const float*)rel_att,
                                  (const float*)rel_msg, wT);
    else       prep_w_body<bf16>((const bf16*)lin_w, (const bf16*)k_w, (const bf16*)q_w,
                                 (const bf16*)v_w, (const bf16*)a_w, (const bf16*)rel_att,
                                 (const bf16*)rel_msg, wT);
}

// ---- bias prep (fp32, same mat indexing) + rel_p + skip ---------------------
template <typename T>
__device__ __forceinline__ void prep_misc_body(const T* lin_b, const T* k_b, const T* q_b,
                                               const T* v_b, const T* a_b, const T* rel_att,
                                               const T* rel_msg, const T* rel_p, const T* skip,
                                               float* biasall, float* relpf, float* skipf) {
    int mat = blockIdx.x, n = threadIdx.x;  // 18 x 128
    float v;
    if (mat < 2) {
        v = toF(lin_b[mat * 128 + n]);
    } else if (mat < 14) {
        int m2 = mat - 2, lt = m2 / 3, op = m2 % 3;
        if (op == 1) {
            v = toF(q_b[lt * 128 + n]);
        } else {
            const T* b = (op == 0 ? k_b : v_b) + lt * 128;
            const T* rl = (op == 0 ? rel_att : rel_msg) + (size_t)lt * 4096;
            int hh = n >> 5, jj = n & 31;
            float s = 0.f;
#pragma unroll 8
            for (int d = 0; d < 32; d++)
                s += toF(b[hh * 32 + d]) * toF(rl[(hh * 32 + d) * 32 + jj]);
            v = s;
        }
    } else {
        v = toF(a_b[(mat - 14) * 128 + n]);
    }
    biasall[mat * 128 + n] = v;
    if (mat == 0 && n < 16) relpf[n] = toF(rel_p[n]);   // [L][NE][H] flat
    if (mat == 1 && n < 4) skipf[n] = toF(skip[n]);     // [L][NT] flat
}
__global__ void prep_misc_kernel(const void* lin_b, const void* k_b, const void* q_b,
                                 const void* v_b, const void* a_b, const void* rel_att,
                                 const void* rel_msg, const void* rel_p, const void* skip,
                                 float* biasall, float* relpf, float* skipf, const int* flag) {
    if (*flag) prep_misc_body<float>((const float*)lin_b, (const float*)k_b, (const float*)q_b,
                                     (const float*)v_b, (const float*)a_b, (const float*)rel_att,
                                     (const float*)rel_msg, (const float*)rel_p, (const float*)skip,
                                     biasall, relpf, skipf);
    else       prep_misc_body<bf16>((const bf16*)lin_b, (const bf16*)k_b, (const bf16*)q_b,
                                    (const bf16*)v_b, (const bf16*)a_b, (const bf16*)rel_att,
                                    (const bf16*)rel_msg, (const bf16*)rel_p, (const bf16*)skip,
                                    biasall, relpf, skipf);
}

// ---- MFMA 128x128xK=128 block compute ---------------------------------------
// As: LDS [128][LDSPITCH] bf16 (A tile, rows=nodes).  wT: [128 n][128 k] bf16 global.
// A-frag: m=lane&15, k=quad*8+j (m120); B-frag: n=lane&15, k=quad*8+j;
// D: row=quad*4+reg, col=lane&15 (m89/m91).
__device__ __forceinline__ void mfma_block(const unsigned short* __restrict__ As,
                                           const unsigned short* __restrict__ wT,
                                           const float* __restrict__ bias,
                                           f32x4 acc[4][4], int wr, int wc, int lane) {
    int m16 = lane & 15, quad = lane >> 4;
#pragma unroll
    for (int ni = 0; ni < 4; ni++) {
        float b = bias[wc * 64 + ni * 16 + m16];
        f32x4 iv = {b, b, b, b};
#pragma unroll
        for (int mi = 0; mi < 4; mi++) acc[mi][ni] = iv;
    }
#pragma unroll
    for (int ks = 0; ks < 4; ks++) {
        bf16x8 a[4], bb[4];
#pragma unroll
        for (int mi = 0; mi < 4; mi++)
            a[mi] = *(const bf16x8*)&As[(wr * 64 + mi * 16 + m16) * LDSPITCH + ks * 32 + quad * 8];
#pragma unroll
        for (int ni = 0; ni < 4; ni++)
            bb[ni] = *(const bf16x8*)&wT[((size_t)(wc * 64 + ni * 16 + m16)) * 128 + ks * 32 + quad * 8];
#pragma unroll
        for (int mi = 0; mi < 4; mi++)
#pragma unroll
            for (int ni = 0; ni < 4; ni++)
                acc[mi][ni] = __builtin_amdgcn_mfma_f32_16x16x32_bf16(a[mi], bb[ni], acc[mi][ni], 0, 0, 0);
    }
}

// ---- lin: x -> h = relu(x W + b) * ewsc -------------------------------------
template <bool FP32>
__device__ __forceinline__ void lin_body(const void* __restrict__ x,
                                         const unsigned short* __restrict__ wT,
                                         const float* __restrict__ biasall,
                                         const float* __restrict__ ewsc,
                                         float* __restrict__ h) {
    __shared__ unsigned short As[128 * LDSPITCH];
    int bid = blockIdx.x, tid = threadIdx.x;
    int t = bid / MBLK, nb = (bid % MBLK) * 128;
#pragma unroll
    for (int i = 0; i < 8; i++) {
        int g = i * 256 + tid;
        int row = g >> 4, c8 = (g & 15) * 8;
        int node = nb + row;
        bf16x8 pk;
        unsigned short* pu = (unsigned short*)&pk;
        if (node < NN) {
            if (FP32) {
                const float4* s = (const float4*)((const float*)x + ((size_t)t * NN + node) * 128 + c8);
                float4 f0 = s[0], f1 = s[1];
                pu[0] = f2bits(f0.x); pu[1] = f2bits(f0.y); pu[2] = f2bits(f0.z); pu[3] = f2bits(f0.w);
                pu[4] = f2bits(f1.x); pu[5] = f2bits(f1.y); pu[6] = f2bits(f1.z); pu[7] = f2bits(f1.w);
            } else {
                pk = *(const bf16x8*)((const unsigned short*)x + ((size_t)t * NN + node) * 128 + c8);
            }
        } else {
#pragma unroll
            for (int jj = 0; jj < 8; jj++) pu[jj] = 0;
        }
        *(bf16x8*)&As[row * LDSPITCH + c8] = pk;
    }
    __syncthreads();
    int wave = tid >> 6, lane = tid & 63;
    int wr = wave >> 1, wc = wave & 1;
    int m16 = lane & 15, quad = lane >> 4;
    f32x4 acc[4][4];
    mfma_block(As, wT + (size_t)t * 16384, biasall + t * 128, acc, wr, wc, lane);
#pragma unroll
    for (int mi = 0; mi < 4; mi++)
#pragma unroll
        for (int r = 0; r < 4; r++) {
            int node = nb + wr * 64 + mi * 16 + quad * 4 + r;
            if (node < NN) {
                float es = ewsc[t * NN + node];
#pragma unroll
                for (int ni = 0; ni < 4; ni++) {
                    int chan = wc * 64 + ni * 16 + m16;
                    h[((size_t)t * NN + node) * 128 + chan] = fmaxf(acc[mi][ni][r], 0.f) * es;
                }
            }
        }
}
__global__ void __launch_bounds__(256) lin_gemm(const void* x, const unsigned short* wT,
                                                const float* biasall, const float* ewsc,
                                                float* h, const int* flag) {
    if (*flag) lin_body<true>(x, wT, biasall, ewsc, h);
    else       lin_body<false>(x, wT, biasall, ewsc, h);
}

// ---- kqv: h -> k_rel (bf16), q (fp32), v_rel (bf16), rel folded into W ------
__global__ void __launch_bounds__(256) kqv_gemm(const float* __restrict__ h,
                                                const unsigned short* __restrict__ wTall,
                                                const float* __restrict__ biasall, int l,
                                                unsigned short* __restrict__ kk,
                                                float* __restrict__ qq,
                                                unsigned short* __restrict__ vv) {
    __shared__ unsigned short As[128 * LDSPITCH];
    int bid = blockIdx.x, tid = threadIdx.x;
    int t = bid / MBLK, nb = (bid % MBLK) * 128;
    int lt = l * 2 + t;
#pragma unroll
    for (int i = 0; i < 8; i++) {
        int g = i * 256 + tid;
        int row = g >> 4, c8 = (g & 15) * 8;
        int node = nb + row;
        bf16x8 pk;
        unsigned short* pu = (unsigned short*)&pk;
        if (node < NN) {
            const float4* s = (const float4*)(h + ((size_t)t * NN + node) * 128 + c8);
            float4 f0 = s[0], f1 = s[1];
            pu[0] = f2bits(f0.x); pu[1] = f2bits(f0.y); pu[2] = f2bits(f0.z); pu[3] = f2bits(f0.w);
            pu[4] = f2bits(f1.x); pu[5] = f2bits(f1.y); pu[6] = f2bits(f1.z); pu[7] = f2bits(f1.w);
        } else {
#pragma unroll
            for (int jj = 0; jj < 8; jj++) pu[jj] = 0;
        }
        *(bf16x8*)&As[row * LDSPITCH + c8] = pk;
    }
    __syncthreads();
    int wave = tid >> 6, lane = tid & 63;
    int wr = wave >> 1, wc = wave & 1;
    int m16 = lane & 15, quad = lane >> 4;
    f32x4 acc[4][4];
#pragma unroll
    for (int pass = 0; pass < 3; pass++) {
        int mat = 2 + lt * 3 + pass;
        mfma_block(As, wTall + (size_t)mat * 16384, biasall + mat * 128, acc, wr, wc, lane);
#pragma unroll
        for (int mi = 0; mi < 4; mi++)
#pragma unroll
            for (int r = 0; r < 4; r++) {
                int node = nb + wr * 64 + mi * 16 + quad * 4 + r;
                if (node < NN) {
#pragma unroll
                    for (int ni = 0; ni < 4; ni++) {
                        int chan = wc * 64 + ni * 16 + m16;
                        size_t io = ((size_t)t * NN + node) * 128 + chan;
                        float v = acc[mi][ni][r];
                        if (pass == 0) kk[io] = f2bits(v);
                        else if (pass == 1) qq[io] = v;
                        else vv[io] = f2bits(v);
                    }
                }
            }
    }
}

// ---- per-dst online-softmax aggregation (64 lanes/dst, 2ch/lane, 2 streams) -
// aggbase may alias qbase (each wave reads its q before writing its agg row).
__global__ void __launch_bounds__(256) agg_kernel(const float* __restrict__ qbase,
                                                  const unsigned short* __restrict__ kbase,
                                                  const unsigned short* __restrict__ vbase,
                                                  const int* __restrict__ srcb,
                                                  const int* __restrict__ offs,
                                                  const float* __restrict__ relpf, int le,
                                                  float* __restrict__ aggbase) {
    int dst = blockIdx.x * 4 + (threadIdx.x >> 6);
    int lane = threadIdx.x & 63;
    int c0 = lane * 2;
    int head = lane >> 4;
    int beg = offs[dst], end = offs[dst + 1];
    size_t rowo = (size_t)dst * 128 + c0;
    if (beg >= end) { *(float2*)&aggbase[rowo] = make_float2(0.f, 0.f); return; }
    float2 qv = *(const float2*)&qbase[rowo];
    float scale = relpf[le * 4 + head] * 0.17677669529663687f;  // rel_p / sqrt(32)
    float mA = -3.0e38f, lA = 0.f, xA = 0.f, yA = 0.f;
    float mB = -3.0e38f, lB = 0.f, xB = 0.f, yB = 0.f;
    int j = beg;
    for (; j + 1 < end; j += 2) {
        int s0 = srcb[j], s1 = srcb[j + 1];
        unsigned k0 = *(const unsigned*)&kbase[(size_t)s0 * 128 + c0];
        unsigned k1 = *(const unsigned*)&kbase[(size_t)s1 * 128 + c0];
        unsigned v0 = *(const unsigned*)&vbase[(size_t)s0 * 128 + c0];
        unsigned v1 = *(const unsigned*)&vbase[(size_t)s1 * 128 + c0];
        float p0 = qv.x * bits2f((unsigned short)k0) + qv.y * bits2f((unsigned short)(k0 >> 16));
        float p1 = qv.x * bits2f((unsigned short)k1) + qv.y * bits2f((unsigned short)(k1 >> 16));
#pragma unroll
        for (int off = 8; off > 0; off >>= 1) {   // reduce within 16-lane head group
            p0 += __shfl_xor(p0, off, 64);
            p1 += __shfl_xor(p1, off, 64);
        }
        float sc0 = p0 * scale, sc1 = p1 * scale;
        float mn = fmaxf(mA, sc0);
        float e0 = __expf(sc0 - mn), rs = __expf(mA - mn);
        lA = lA * rs + e0;
        xA = xA * rs + e0 * bits2f((unsigned short)v0);
        yA = yA * rs + e0 * bits2f((unsigned short)(v0 >> 16));
        mA = mn;
        mn = fmaxf(mB, sc1);
        float e1 = __expf(sc1 - mn); rs = __expf(mB - mn);
        lB = lB * rs + e1;
        xB = xB * rs + e1 * bits2f((unsigned short)v1);
        yB = yB * rs + e1 * bits2f((unsigned short)(v1 >> 16));
        mB = mn;
    }
    if (j < end) {
        int s0 = srcb[j];
        unsigned k0 = *(const unsigned*)&kbase[(size_t)s0 * 128 + c0];
        unsigned v0 = *(const unsigned*)&vbase[(size_t)s0 * 128 + c0];
        float p0 = qv.x * bits2f((unsigned short)k0) + qv.y * bits2f((unsigned short)(k0 >> 16));
#pragma unroll
        for (int off = 8; off > 0; off >>= 1) p0 += __shfl_xor(p0, off, 64);
        float sc0 = p0 * scale;
        float mn = fmaxf(mA, sc0);
        float e0 = __expf(sc0 - mn), rs = __expf(mA - mn);
        lA = lA * rs + e0;
        xA = xA * rs + e0 * bits2f((unsigned short)v0);
        yA = yA * rs + e0 * bits2f((unsigned short)(v0 >> 16));
        mA = mn;
    }
    float mM = fmaxf(mA, mB);
    float wA = __expf(mA - mM), wB = __expf(mB - mM);
    float lsum = lA * wA + lB * wB + 1e-16f;
    *(float2*)&aggbase[rowo] = make_float2((xA * wA + xB * wB) / lsum,
                                           (yA * wA + yB * wB) / lsum);
}

// ---- outproj: h' = beta*(gelu(agg) W_a + b_a) + (1-beta)*h; final -> out ----
__global__ void __launch_bounds__(256) outproj_gemm(const float* __restrict__ agg,
                                                    const unsigned short* __restrict__ wTall,
                                                    const float* __restrict__ biasall,
                                                    const float* __restrict__ skipf, int l,
                                                    float* __restrict__ h, int last,
                                                    void* __restrict__ outp,
                                                    const int* __restrict__ flag) {
    __shared__ unsigned short As[128 * LDSPITCH];
    int bid = blockIdx.x, tid = threadIdx.x;
    int t = bid / MBLK, nb = (bid % MBLK) * 128;
    int lt = l * 2 + t;
#pragma unroll
    for (int i = 0; i < 8; i++) {
        int g = i * 256 + tid;
        int row = g >> 4, c8 = (g & 15) * 8;
        int node = nb + row;
        bf16x8 pk;
        unsigned short* pu = (unsigned short*)&pk;
        if (node < NN) {
            const float4* s = (const float4*)(agg + ((size_t)t * NN + node) * 128 + c8);
            float4 f0 = s[0], f1 = s[1];
            float g8[8] = {f0.x, f0.y, f0.z, f0.w, f1.x, f1.y, f1.z, f1.w};
#pragma unroll
            for (int jj = 0; jj < 8; jj++) {
                float gv = g8[jj];
                pu[jj] = f2bits(0.5f * gv * (1.0f + erff(gv * 0.70710678118654752f)));
            }
        } else {
#pragma unroll
            for (int jj = 0; jj < 8; jj++) pu[jj] = 0;
        }
        *(bf16x8*)&As[row * LDSPITCH + c8] = pk;
    }
    __syncthreads();
    int wave = tid >> 6, lane = tid & 63;
    int wr = wave >> 1, wc = wave & 1;
    int m16 = lane & 15, quad = lane >> 4;
    int mat = 14 + lt;
    f32x4 acc[4][4];
    mfma_block(As, wTall + (size_t)mat * 16384, biasall + mat * 128, acc, wr, wc, lane);
    float beta = sigm(skipf[lt]);
    int fl = *flag;
#pragma unroll
    for (int mi = 0; mi < 4; mi++)
#pragma unroll
        for (int r = 0; r < 4; r++) {
            int node = nb + wr * 64 + mi * 16 + quad * 4 + r;
            if (node < NN) {
#pragma unroll
                for (int ni = 0; ni < 4; ni++) {
                    int chan = wc * 64 + ni * 16 + m16;
                    size_t io = ((size_t)t * NN + node) * 128 + chan;
                    float nv = beta * acc[mi][ni][r] + (1.0f - beta) * h[io];
                    h[io] = nv;
                    if (last) {
                        if (fl) ((float*)outp)[io] = nv;
                        else    ((bf16*)outp)[io] = __float2bfloat16(nv);
                    }
                }
            }
        }
}

extern "C" void kernel_launch(void* const* d_in, const int* in_sizes, int n_in,
                              void* d_out, int out_size, void* d_ws, size_t ws_size,
                              hipStream_t stream) {
    const void* x      = d_in[0];
    const int*  ei     = (const int*)d_in[1];
    const void* ew     = d_in[2];
    const void* lin_w  = d_in[3];
    const void* lin_b  = d_in[4];
    const void* k_w    = d_in[5];
    const void* k_b    = d_in[6];
    const void* q_w    = d_in[7];
    const void* q_b    = d_in[8];
    const void* v_w    = d_in[9];
    const void* v_b    = d_in[10];
    const void* a_w    = d_in[11];
    const void* a_b    = d_in[12];
    const void* skip   = d_in[13];
    const void* rel_att = d_in[14];
    const void* rel_msg = d_in[15];
    const void* rel_p  = d_in[16];

    char* p = (char*)d_ws;
    auto alloc = [&](size_t bytes) -> char* {
        char* r = p;
        p += (bytes + 255) & ~(size_t)255;
        return r;
    };
    int* flag     = (int*)alloc(sizeof(int));
    int* counts   = (int*)alloc(sizeof(int) * NE * NN);
    int* offs     = (int*)alloc(sizeof(int) * NE * (NN + 1));
    int* bsum     = (int*)alloc(sizeof(int) * NE * NCHUNK);
    int* cursor   = (int*)alloc(sizeof(int) * NE * NN);
    int* srcb     = (int*)alloc(sizeof(int) * NE * NEDGE);
    int* lastidx  = (int*)alloc(sizeof(int) * NT * NN);
    unsigned short* wTall = (unsigned short*)alloc(sizeof(short) * 18 * 16384);  // 576 KB
    float* biasall = (float*)alloc(sizeof(float) * 18 * 128);
    float* relpf   = (float*)alloc(sizeof(float) * 16);
    float* skipf   = (float*)alloc(sizeof(float) * 4);
    float* ewsc    = (float*)alloc(sizeof(float) * NT * NN);
    float* h       = (float*)alloc(sizeof(float) * NT * NN * HID);          // 51.2 MB
    float* qq      = (float*)alloc(sizeof(float) * NT * NN * HID);          // 51.2 MB (agg aliases)
    unsigned short* kk = (unsigned short*)alloc(sizeof(short) * NT * NN * HID);  // 25.6 MB
    unsigned short* vv = (unsigned short*)alloc(sizeof(short) * NT * NN * HID);  // 25.6 MB
    float* agg = qq;

    hipMemsetAsync(lastidx, 0xFF, sizeof(int) * NT * NN, stream);
    hipMemsetAsync(counts, 0, sizeof(int) * NE * NN, stream);

    detect_kernel<<<1, 64, 0, stream>>>(x, flag);
    lastcnt_kernel<<<(NE * NEDGE + 255) / 256, 256, 0, stream>>>(ei, lastidx, counts);
    prep_w_kernel<<<18 * 64, 256, 0, stream>>>(lin_w, k_w, q_w, v_w, a_w, rel_att, rel_msg,
                                               wTall, flag);
    prep_misc_kernel<<<18, 128, 0, stream>>>(lin_b, k_b, q_b, v_b, a_b, rel_att, rel_msg,
                                             rel_p, skip, biasall, relpf, skipf, flag);
    scan1_kernel<<<NE * NCHUNK, 256, 0, stream>>>(counts, offs, bsum);
    scan2_kernel<<<NE, 256, 0, stream>>>(bsum);
    scan3_kernel<<<NE * NCHUNK, 256, 0, stream>>>(offs, bsum, cursor);
    fill_kernel<<<(NE * NEDGE + 255) / 256, 256, 0, stream>>>(ei, cursor, srcb);
    ewsc_kernel<<<(NT * NN + 255) / 256, 256, 0, stream>>>(ew, lastidx, ewsc, flag);

    lin_gemm<<<NT * MBLK, 256, 0, stream>>>(x, wTall, biasall, ewsc, h, flag);

    for (int l = 0; l < NL; l++) {
        kqv_gemm<<<NT * MBLK, 256, 0, stream>>>(h, wTall, biasall, l, kk, qq, vv);
        for (int e = 0; e < NE; e++) {
            int s = e, t = 1 - e;     // EDGE_SRC=(0,1), EDGE_DST=(1,0)
            int le = l * 2 + e;
            agg_kernel<<<NN / 4, 256, 0, stream>>>(
                qq + (size_t)t * NN * HID,
                kk + (size_t)s * NN * HID, vv + (size_t)s * NN * HID,
                srcb + (size_t)e * NEDGE, offs + (size_t)e * (NN + 1),
                relpf, le, agg + (size_t)t * NN * HID);
        }
        outproj_gemm<<<NT * MBLK, 256, 0, stream>>>(agg, wTall, biasall, skipf, l, h,
                                                    (l == NL - 1) ? 1 : 0, d_out, flag);
    }
}

// Round 5
// 570.165 us; speedup vs baseline: 2.5863x; 1.1672x over previous
//
#include <hip/hip_runtime.h>
#include <hip/hip_bf16.h>
#include <math.h>

typedef __hip_bfloat16 bf16;
typedef __attribute__((ext_vector_type(8))) short bf16x8;   // MFMA A/B frag (4 VGPRs)
typedef __attribute__((ext_vector_type(4))) float f32x4;    // MFMA C/D frag

#define NT 2
#define NE 2
#define NN 50000
#define HID 128
#define NH 4
#define DD 32
#define NL 2
#define NEDGE 400000
#define NCHUNK 196      // ceil(50000/256)
#define MBLK64 782      // ceil(50000/64)
#define AGGB 12500      // NN/4 blocks per edge type
#define WPITCH 136      // LDS W row pitch (elems): 272 B, 16B-aligned, 2-way banks (free)

__device__ __forceinline__ float b2f(bf16 v) { return __bfloat162float(v); }
__device__ __forceinline__ float toF(float v) { return v; }
__device__ __forceinline__ float toF(bf16 v) { return b2f(v); }
__device__ __forceinline__ float sigm(float x) { return 1.0f / (1.0f + __expf(-x)); }
__device__ __forceinline__ unsigned short f2bits(float f) {
    bf16 h = __float2bfloat16(f);
    unsigned short b; __builtin_memcpy(&b, &h, 2); return b;
}
__device__ __forceinline__ float bits2f(unsigned short b) {
    unsigned u = ((unsigned)b) << 16; float f; __builtin_memcpy(&f, &u, 4); return f;
}

// ---- input dtype detection (0 = bf16, 1 = fp32) -----------------------------
__global__ void detect_kernel(const void* __restrict__ x, int* __restrict__ flag) {
    int lane = threadIdx.x;  // 64
    const unsigned short* u = (const unsigned short*)x;
    int cnt = 0;
    for (int i = 0; i < 4; i++) {
        unsigned short w = u[lane * 4 + i];
        int e = (w >> 7) & 0xFF;
        if (e >= 110 && e <= 135) cnt++;
    }
    for (int off = 32; off > 0; off >>= 1) cnt += __shfl_xor(cnt, off, 64);
    if (lane == 0) *flag = (cnt > 200) ? 0 : 1;
}

// ---- merged last-edge-index + dst-degree count ------------------------------
__global__ void lastcnt_kernel(const int* __restrict__ ei, int* __restrict__ lastidx,
                               int* __restrict__ counts) {
    int idx = blockIdx.x * blockDim.x + threadIdx.x;
    if (idx >= NE * NEDGE) return;
    int e = idx / NEDGE, j = idx % NEDGE;
    int src = ei[(e * 2 + 0) * NEDGE + j];   // EDGE_SRC=(0,1): src type == e
    int dst = ei[(e * 2 + 1) * NEDGE + j];
    atomicMax(&lastidx[e * NN + src], j);
    atomicAdd(&counts[e * NN + dst], 1);
}

// ---- CSR scans --------------------------------------------------------------
__global__ void scan1_kernel(const int* __restrict__ counts, int* __restrict__ offs,
                             int* __restrict__ bsum) {
    int e = blockIdx.x / NCHUNK, cb = blockIdx.x % NCHUNK;
    int tid = threadIdx.x;
    int idx = cb * 256 + tid;
    int v = (idx < NN) ? counts[e * NN + idx] : 0;
    __shared__ int sb[256];
    sb[tid] = v; __syncthreads();
    for (int off = 1; off < 256; off <<= 1) {
        int a = (tid >= off) ? sb[tid - off] : 0;
        __syncthreads();
        sb[tid] += a;
        __syncthreads();
    }
    if (idx < NN) offs[e * (NN + 1) + idx] = sb[tid] - v;
    if (tid == 255) bsum[e * NCHUNK + cb] = sb[255];
}

__global__ void scan2_kernel(int* __restrict__ bsum) {
    int e = blockIdx.x;
    int tid = threadIdx.x;
    int v = (tid < NCHUNK) ? bsum[e * NCHUNK + tid] : 0;
    __shared__ int sb[256];
    sb[tid] = v; __syncthreads();
    for (int off = 1; off < 256; off <<= 1) {
        int a = (tid >= off) ? sb[tid - off] : 0;
        __syncthreads();
        sb[tid] += a;
        __syncthreads();
    }
    if (tid < NCHUNK) bsum[e * NCHUNK + tid] = sb[tid] - v;
}

__global__ void scan3_kernel(int* __restrict__ offs, const int* __restrict__ bsum,
                             int* __restrict__ cursor) {
    int e = blockIdx.x / NCHUNK, cb = blockIdx.x % NCHUNK;
    int idx = cb * 256 + threadIdx.x;
    if (idx < NN) {
        int v = offs[e * (NN + 1) + idx] + bsum[e * NCHUNK + cb];
        offs[e * (NN + 1) + idx] = v;
        cursor[e * NN + idx] = v;
    } else if (idx == NN) {
        offs[e * (NN + 1) + NN] = NEDGE;
    }
}

__global__ void fill_kernel(const int* __restrict__ ei, int* __restrict__ cursor,
                            int* __restrict__ srcb) {
    int idx = blockIdx.x * blockDim.x + threadIdx.x;
    if (idx >= NE * NEDGE) return;
    int e = idx / NEDGE, j = idx % NEDGE;
    int src = ei[(e * 2 + 0) * NEDGE + j];
    int dst = ei[(e * 2 + 1) * NEDGE + j];
    int pos = atomicAdd(&cursor[e * NN + dst], 1);
    srcb[e * NEDGE + pos] = src;
}

// ---- per-node sigmoid(ew[last]) scale ---------------------------------------
template <typename T>
__device__ __forceinline__ void ewsc_body(const T* __restrict__ ew, const int* __restrict__ lastidx,
                                          float* __restrict__ ewsc) {
    int idx = blockIdx.x * blockDim.x + threadIdx.x;
    if (idx >= NT * NN) return;
    int t = idx / NN;
    int li = lastidx[idx];
    ewsc[idx] = (li >= 0) ? sigm(toF(ew[(size_t)t * NEDGE + li])) : 1.0f;
}
__global__ void ewsc_kernel(const void* ew, const int* lastidx, float* ewsc, const int* flag) {
    if (*flag) ewsc_body<float>((const float*)ew, lastidx, ewsc);
    else       ewsc_body<bf16>((const bf16*)ew, lastidx, ewsc);
}

// ---- weight prep: transpose + fold rel into K/V weights ---------------------
// wT layout (bf16, [n][k]): mat 0,1 = linT; mat 2+lt*3+{0,1,2} = kT_fold,qT,vT_fold
// (lt = l*2+t); mat 14+lt = aT.
template <typename T>
__device__ __forceinline__ void prep_w_body(const T* lin_w, const T* k_w, const T* q_w,
                                            const T* v_w, const T* a_w, const T* rel_att,
                                            const T* rel_msg, unsigned short* wT) {
    int bid = blockIdx.x, tid = threadIdx.x;
    int mat = bid >> 6;
    int elem = (bid & 63) * 256 + tid;
    int n = elem >> 7, k = elem & 127;
    float v;
    if (mat < 2) {
        v = toF(lin_w[(size_t)mat * 16384 + k * 128 + n]);
    } else if (mat < 14) {
        int m2 = mat - 2, lt = m2 / 3, op = m2 % 3;
        if (op == 1) {
            v = toF(q_w[(size_t)lt * 16384 + k * 128 + n]);
        } else {
            const T* w = (op == 0 ? k_w : v_w) + (size_t)lt * 16384 + k * 128;
            const T* rl = (op == 0 ? rel_att : rel_msg) + (size_t)lt * 4096;  // e == t
            int hh = n >> 5, jj = n & 31;
            float s = 0.f;
#pragma unroll 8
            for (int d = 0; d < 32; d++)
                s += toF(w[hh * 32 + d]) * toF(rl[(hh * 32 + d) * 32 + jj]);
            v = s;
        }
    } else {
        v = toF(a_w[(size_t)(mat - 14) * 16384 + k * 128 + n]);
    }
    wT[(size_t)mat * 16384 + n * 128 + k] = f2bits(v);
}
__global__ void prep_w_kernel(const void* lin_w, const void* k_w, const void* q_w,
                              const void* v_w, const void* a_w, const void* rel_att,
                              const void* rel_msg, unsigned short* wT, const int* flag) {
    if (*flag) prep_w_body<float>((const float*)lin_w, (const float*)k_w, (const float*)q_w,
                                  (const float*)v_w, (const float*)a_w, (const float*)rel_att,
                                  (const float*)rel_msg, wT);
    else       prep_w_body<bf16>((const bf16*)lin_w, (const bf16*)k_w, (const bf16*)q_w,
                                 (const bf16*)v_w, (const bf16*)a_w, (const bf16*)rel_att,
                                 (const bf16*)rel_msg, wT);
}

// ---- bias prep (fp32) + rel_p + skip ----------------------------------------
template <typename T>
__device__ __forceinline__ void prep_misc_body(const T* lin_b, const T* k_b, const T* q_b,
                                               const T* v_b, const T* a_b, const T* rel_att,
                                               const T* rel_msg, const T* rel_p, const T* skip,
                                               float* biasall, float* relpf, float* skipf) {
    int mat = blockIdx.x, n = threadIdx.x;  // 18 x 128
    float v;
    if (mat < 2) {
        v = toF(lin_b[mat * 128 + n]);
    } else if (mat < 14) {
        int m2 = mat - 2, lt = m2 / 3, op = m2 % 3;
        if (op == 1) {
            v = toF(q_b[lt * 128 + n]);
        } else {
            const T* b = (op == 0 ? k_b : v_b) + lt * 128;
            const T* rl = (op == 0 ? rel_att : rel_msg) + (size_t)lt * 4096;
            int hh = n >> 5, jj = n & 31;
            float s = 0.f;
#pragma unroll 8
            for (int d = 0; d < 32; d++)
                s += toF(b[hh * 32 + d]) * toF(rl[(hh * 32 + d) * 32 + jj]);
            v = s;
        }
    } else {
        v = toF(a_b[(mat - 14) * 128 + n]);
    }
    biasall[mat * 128 + n] = v;
    if (mat == 0 && n < 16) relpf[n] = toF(rel_p[n]);
    if (mat == 1 && n < 4) skipf[n] = toF(skip[n]);
}
__global__ void prep_misc_kernel(const void* lin_b, const void* k_b, const void* q_b,
                                 const void* v_b, const void* a_b, const void* rel_att,
                                 const void* rel_msg, const void* rel_p, const void* skip,
                                 float* biasall, float* relpf, float* skipf, const int* flag) {
    if (*flag) prep_misc_body<float>((const float*)lin_b, (const float*)k_b, (const float*)q_b,
                                     (const float*)v_b, (const float*)a_b, (const float*)rel_att,
                                     (const float*)rel_msg, (const float*)rel_p, (const float*)skip,
                                     biasall, relpf, skipf);
    else       prep_misc_body<bf16>((const bf16*)lin_b, (const bf16*)k_b, (const bf16*)q_b,
                                    (const bf16*)v_b, (const bf16*)a_b, (const bf16*)rel_att,
                                    (const bf16*)rel_msg, (const bf16*)rel_p, (const bf16*)skip,
                                    biasall, relpf, skipf);
}

// ---- shared GEMM helpers ----------------------------------------------------
// Block: 256 thr = 4 waves; each wave owns 16 rows x 128 cols. W in LDS [128][WPITCH].
__device__ __forceinline__ void stage_w(unsigned short* __restrict__ Wl,
                                        const unsigned short* __restrict__ wmat, int tid) {
#pragma unroll
    for (int i = 0; i < 8; i++) {
        int c = i * 256 + tid;           // 2048 chunks of 8
        int n = c >> 4, ko = (c & 15) * 8;
        *(bf16x8*)&Wl[n * WPITCH + ko] = *(const bf16x8*)&wmat[n * 128 + ko];
    }
}

__device__ __forceinline__ void mfma_pass(const unsigned short* __restrict__ Wl,
                                          const bf16x8 af[4], const float* __restrict__ bias,
                                          f32x4 acc[8], int m16, int quad) {
#pragma unroll
    for (int ni = 0; ni < 8; ni++) {
        float b = bias[ni * 16 + m16];
        f32x4 iv = {b, b, b, b};
        acc[ni] = iv;
    }
#pragma unroll
    for (int ks = 0; ks < 4; ks++) {
        bf16x8 a = af[ks];
#pragma unroll
        for (int ni = 0; ni < 8; ni++) {
            bf16x8 bb = *(const bf16x8*)&Wl[(ni * 16 + m16) * WPITCH + ks * 32 + quad * 8];
            acc[ni] = __builtin_amdgcn_mfma_f32_16x16x32_bf16(a, bb, acc[ni], 0, 0, 0);
        }
    }
}

// ---- lin: x -> h = relu(x W + b) * ewsc  (h fp32) ---------------------------
template <bool FP32>
__device__ __forceinline__ void lin_body(const void* __restrict__ x,
                                         const unsigned short* __restrict__ wT,
                                         const float* __restrict__ biasall,
                                         const float* __restrict__ ewsc,
                                         float* __restrict__ h) {
    __shared__ unsigned short Wl[128 * WPITCH];
    int bid = blockIdx.x, tid = threadIdx.x;
    int t = bid / MBLK64, nb = (bid % MBLK64) * 64;
    int wave = tid >> 6, lane = tid & 63;
    int m16 = lane & 15, quad = lane >> 4;
    stage_w(Wl, wT + (size_t)t * 16384, tid);
    int arow = nb + wave * 16 + m16;
    int arc = arow < NN ? arow : NN - 1;
    size_t abase = ((size_t)t * NN + arc) * 128;
    bf16x8 af[4];
#pragma unroll
    for (int ks = 0; ks < 4; ks++) {
        if (FP32) {
            const float4* s = (const float4*)((const float*)x + abase + ks * 32 + quad * 8);
            float4 f0 = s[0], f1 = s[1];
            unsigned short* pu = (unsigned short*)&af[ks];
            pu[0] = f2bits(f0.x); pu[1] = f2bits(f0.y); pu[2] = f2bits(f0.z); pu[3] = f2bits(f0.w);
            pu[4] = f2bits(f1.x); pu[5] = f2bits(f1.y); pu[6] = f2bits(f1.z); pu[7] = f2bits(f1.w);
        } else {
            af[ks] = *(const bf16x8*)((const unsigned short*)x + abase + ks * 32 + quad * 8);
        }
    }
    __syncthreads();
    f32x4 acc[8];
    mfma_pass(Wl, af, biasall + t * 128, acc, m16, quad);
#pragma unroll
    for (int r = 0; r < 4; r++) {
        int node = nb + wave * 16 + quad * 4 + r;
        if (node < NN) {
            float es = ewsc[t * NN + node];
            size_t ro = ((size_t)t * NN + node) * 128;
#pragma unroll
            for (int ni = 0; ni < 8; ni++)
                h[ro + ni * 16 + m16] = fmaxf(acc[ni][r], 0.f) * es;
        }
    }
}
__global__ void __launch_bounds__(256, 4) lin_gemm(const void* x, const unsigned short* wT,
                                                   const float* biasall, const float* ewsc,
                                                   float* h, const int* flag) {
    if (*flag) lin_body<true>(x, wT, biasall, ewsc, h);
    else       lin_body<false>(x, wT, biasall, ewsc, h);
}

// ---- kqv: h -> k_rel / q / v_rel (all bf16); rel folded into W --------------
__global__ void __launch_bounds__(256, 4) kqv_gemm(const float* __restrict__ h,
                                                   const unsigned short* __restrict__ wTall,
                                                   const float* __restrict__ biasall, int l,
                                                   unsigned short* __restrict__ kk,
                                                   unsigned short* __restrict__ qq,
                                                   unsigned short* __restrict__ vv) {
    __shared__ unsigned short Wl[128 * WPITCH];
    int bid = blockIdx.x, tid = threadIdx.x;
    int t = bid / MBLK64, nb = (bid % MBLK64) * 64;
    int lt = l * 2 + t;
    int wave = tid >> 6, lane = tid & 63;
    int m16 = lane & 15, quad = lane >> 4;
    int arow = nb + wave * 16 + m16;
    int arc = arow < NN ? arow : NN - 1;
    size_t abase = ((size_t)t * NN + arc) * 128;
    bf16x8 af[4];
#pragma unroll
    for (int ks = 0; ks < 4; ks++) {
        const float4* s = (const float4*)(h + abase + ks * 32 + quad * 8);
        float4 f0 = s[0], f1 = s[1];
        unsigned short* pu = (unsigned short*)&af[ks];
        pu[0] = f2bits(f0.x); pu[1] = f2bits(f0.y); pu[2] = f2bits(f0.z); pu[3] = f2bits(f0.w);
        pu[4] = f2bits(f1.x); pu[5] = f2bits(f1.y); pu[6] = f2bits(f1.z); pu[7] = f2bits(f1.w);
    }
    f32x4 acc[8];
#pragma unroll
    for (int pass = 0; pass < 3; pass++) {
        int mat = 2 + lt * 3 + pass;
        __syncthreads();   // prior pass's MFMA reads done before restaging W
        stage_w(Wl, wTall + (size_t)mat * 16384, tid);
        __syncthreads();
        mfma_pass(Wl, af, biasall + mat * 128, acc, m16, quad);
        unsigned short* dst = (pass == 0) ? kk : (pass == 1 ? qq : vv);
#pragma unroll
        for (int r = 0; r < 4; r++) {
            int node = nb + wave * 16 + quad * 4 + r;
            if (node < NN) {
                size_t ro = ((size_t)t * NN + node) * 128;
#pragma unroll
                for (int ni = 0; ni < 8; ni++)
                    dst[ro + ni * 16 + m16] = f2bits(acc[ni][r]);
            }
        }
    }
}

// ---- merged-edge-type online-softmax aggregation ----------------------------
// 1 wave per dst; 4 bf16 chans/lane; two half-wave streams (lanes<32 = even
// edges, >=32 = odd), merged exactly at the end. aggb aliases qq (row read
// before row write, per wave).
__global__ void __launch_bounds__(256) agg_kernel(const unsigned short* __restrict__ qq,
                                                  const unsigned short* __restrict__ kk,
                                                  const unsigned short* __restrict__ vv,
                                                  const int* __restrict__ srcb,
                                                  const int* __restrict__ offs,
                                                  const float* __restrict__ relpf, int l,
                                                  unsigned short* __restrict__ aggb) {
    int bid = blockIdx.x;
    int e = bid / AGGB;
    int wave = threadIdx.x >> 6, lane = threadIdx.x & 63;
    int dst = (bid % AGGB) * 4 + wave;
    int t = 1 - e;                      // EDGE_DST=(1,0)
    int le = l * 2 + e;
    const int* offs_e = offs + e * (NN + 1);
    const int* srcb_e = srcb + (size_t)e * NEDGE;
    int beg = offs_e[dst], end = offs_e[dst + 1];
    int half = lane >> 5, l5 = lane & 31;
    int ch0 = l5 * 4, head = l5 >> 3;
    size_t rowo = ((size_t)t * NN + dst) * 128 + ch0;
    if (beg >= end) {
        if (!half) *(ushort4*)&aggb[rowo] = make_ushort4(0, 0, 0, 0);
        return;
    }
    ushort4 q4 = *(const ushort4*)&qq[rowo];
    float q0 = bits2f(q4.x), q1 = bits2f(q4.y), q2 = bits2f(q4.z), q3 = bits2f(q4.w);
    float scale = relpf[le * 4 + head] * 0.17677669529663687f;  // rel_p / sqrt(32)
    const unsigned short* kb = kk + (size_t)e * NN * 128;       // EDGE_SRC=(0,1): s == e
    const unsigned short* vb = vv + (size_t)e * NN * 128;
    float m = -3.0e38f, lsum = 0.f, a0 = 0.f, a1 = 0.f, a2 = 0.f, a3 = 0.f;
    int j = beg;
    for (; j + 1 < end; j += 2) {
        int src = srcb_e[j + half];
        size_t so = (size_t)src * 128 + ch0;
        ushort4 k4 = *(const ushort4*)&kb[so];
        ushort4 v4 = *(const ushort4*)&vb[so];
        float p = q0 * bits2f(k4.x) + q1 * bits2f(k4.y) + q2 * bits2f(k4.z) + q3 * bits2f(k4.w);
        p += __shfl_xor(p, 4, 64);
        p += __shfl_xor(p, 2, 64);
        p += __shfl_xor(p, 1, 64);
        float sc = p * scale;
        float mn = fmaxf(m, sc);
        float ee = __expf(sc - mn), rs = __expf(m - mn);
        lsum = lsum * rs + ee;
        a0 = a0 * rs + ee * bits2f(v4.x);
        a1 = a1 * rs + ee * bits2f(v4.y);
        a2 = a2 * rs + ee * bits2f(v4.z);
        a3 = a3 * rs + ee * bits2f(v4.w);
        m = mn;
    }
    if (j < end) {   // odd tail: both halves compute, only stream A absorbs it
        int src = srcb_e[j];
        size_t so = (size_t)src * 128 + ch0;
        ushort4 k4 = *(const ushort4*)&kb[so];
        ushort4 v4 = *(const ushort4*)&vb[so];
        float p = q0 * bits2f(k4.x) + q1 * bits2f(k4.y) + q2 * bits2f(k4.z) + q3 * bits2f(k4.w);
        p += __shfl_xor(p, 4, 64);
        p += __shfl_xor(p, 2, 64);
        p += __shfl_xor(p, 1, 64);
        if (!half) {
            float sc = p * scale;
            float mn = fmaxf(m, sc);
            float ee = __expf(sc - mn), rs = __expf(m - mn);
            lsum = lsum * rs + ee;
            a0 = a0 * rs + ee * bits2f(v4.x);
            a1 = a1 * rs + ee * bits2f(v4.y);
            a2 = a2 * rs + ee * bits2f(v4.z);
            a3 = a3 * rs + ee * bits2f(v4.w);
            m = mn;
        }
    }
    // exact two-stream merge across halves
    float mo = __shfl_xor(m, 32, 64);
    float lo = __shfl_xor(lsum, 32, 64);
    float b0 = __shfl_xor(a0, 32, 64);
    float b1 = __shfl_xor(a1, 32, 64);
    float b2 = __shfl_xor(a2, 32, 64);
    float b3 = __shfl_xor(a3, 32, 64);
    float mm = fmaxf(m, mo);
    float wa = __expf(m - mm), wb = __expf(mo - mm);
    float den = lsum * wa + lo * wb + 1e-16f;
    if (!half) {
        ushort4 o;
        o.x = f2bits((a0 * wa + b0 * wb) / den);
        o.y = f2bits((a1 * wa + b1 * wb) / den);
        o.z = f2bits((a2 * wa + b2 * wb) / den);
        o.w = f2bits((a3 * wa + b3 * wb) / den);
        *(ushort4*)&aggb[rowo] = o;
    }
}

// ---- outproj: h' = beta*(gelu(agg) W_a + b_a) + (1-beta)*h; final -> out ----
__global__ void __launch_bounds__(256, 4) outproj_gemm(const unsigned short* __restrict__ aggb,
                                                       const unsigned short* __restrict__ wTall,
                                                       const float* __restrict__ biasall,
                                                       const float* __restrict__ skipf, int l,
                                                       float* __restrict__ h, int last,
                                                       void* __restrict__ outp,
                                                       const int* __restrict__ flag) {
    __shared__ unsigned short Wl[128 * WPITCH];
    int bid = blockIdx.x, tid = threadIdx.x;
    int t = bid / MBLK64, nb = (bid % MBLK64) * 64;
    int lt = l * 2 + t;
    int wave = tid >> 6, lane = tid & 63;
    int m16 = lane & 15, quad = lane >> 4;
    int mat = 14 + lt;
    stage_w(Wl, wTall + (size_t)mat * 16384, tid);
    int arow = nb + wave * 16 + m16;
    int arc = arow < NN ? arow : NN - 1;
    size_t abase = ((size_t)t * NN + arc) * 128;
    bf16x8 af[4];
#pragma unroll
    for (int ks = 0; ks < 4; ks++) {
        bf16x8 raw = *(const bf16x8*)&aggb[abase + ks * 32 + quad * 8];
        const unsigned short* ru = (const unsigned short*)&raw;
        unsigned short* pu = (unsigned short*)&af[ks];
#pragma unroll
        for (int jj = 0; jj < 8; jj++) {
            float g = bits2f(ru[jj]);
            pu[jj] = f2bits(0.5f * g * (1.0f + erff(g * 0.70710678118654752f)));  // exact gelu
        }
    }
    __syncthreads();
    f32x4 acc[8];
    mfma_pass(Wl, af, biasall + mat * 128, acc, m16, quad);
    float beta = sigm(skipf[lt]);
    int fl = *flag;
#pragma unroll
    for (int r = 0; r < 4; r++) {
        int node = nb + wave * 16 + quad * 4 + r;
        if (node < NN) {
            size_t ro = ((size_t)t * NN + node) * 128;
#pragma unroll
            for (int ni = 0; ni < 8; ni++) {
                size_t io = ro + ni * 16 + m16;
                float nv = beta * acc[ni][r] + (1.0f - beta) * h[io];
                h[io] = nv;
                if (last) {
                    if (fl) ((float*)outp)[io] = nv;
                    else    ((bf16*)outp)[io] = __float2bfloat16(nv);
                }
            }
        }
    }
}

extern "C" void kernel_launch(void* const* d_in, const int* in_sizes, int n_in,
                              void* d_out, int out_size, void* d_ws, size_t ws_size,
                              hipStream_t stream) {
    const void* x      = d_in[0];
    const int*  ei     = (const int*)d_in[1];
    const void* ew     = d_in[2];
    const void* lin_w  = d_in[3];
    const void* lin_b  = d_in[4];
    const void* k_w    = d_in[5];
    const void* k_b    = d_in[6];
    const void* q_w    = d_in[7];
    const void* q_b    = d_in[8];
    const void* v_w    = d_in[9];
    const void* v_b    = d_in[10];
    const void* a_w    = d_in[11];
    const void* a_b    = d_in[12];
    const void* skip   = d_in[13];
    const void* rel_att = d_in[14];
    const void* rel_msg = d_in[15];
    const void* rel_p  = d_in[16];

    char* p = (char*)d_ws;
    auto alloc = [&](size_t bytes) -> char* {
        char* r = p;
        p += (bytes + 255) & ~(size_t)255;
        return r;
    };
    int* flag     = (int*)alloc(sizeof(int));
    int* counts   = (int*)alloc(sizeof(int) * NE * NN);
    int* offs     = (int*)alloc(sizeof(int) * NE * (NN + 1));
    int* bsum     = (int*)alloc(sizeof(int) * NE * NCHUNK);
    int* cursor   = (int*)alloc(sizeof(int) * NE * NN);
    int* srcb     = (int*)alloc(sizeof(int) * NE * NEDGE);
    int* lastidx  = (int*)alloc(sizeof(int) * NT * NN);
    unsigned short* wTall = (unsigned short*)alloc(sizeof(short) * 18 * 16384);
    float* biasall = (float*)alloc(sizeof(float) * 18 * 128);
    float* relpf   = (float*)alloc(sizeof(float) * 16);
    float* skipf   = (float*)alloc(sizeof(float) * 4);
    float* ewsc    = (float*)alloc(sizeof(float) * NT * NN);
    float* h       = (float*)alloc(sizeof(float) * NT * NN * HID);               // 51.2 MB fp32
    unsigned short* qq = (unsigned short*)alloc(sizeof(short) * NT * NN * HID);  // 25.6 MB (agg aliases)
    unsigned short* kk = (unsigned short*)alloc(sizeof(short) * NT * NN * HID);  // 25.6 MB
    unsigned short* vv = (unsigned short*)alloc(sizeof(short) * NT * NN * HID);  // 25.6 MB
    unsigned short* aggb = qq;

    hipMemsetAsync(lastidx, 0xFF, sizeof(int) * NT * NN, stream);
    hipMemsetAsync(counts, 0, sizeof(int) * NE * NN, stream);

    detect_kernel<<<1, 64, 0, stream>>>(x, flag);
    lastcnt_kernel<<<(NE * NEDGE + 255) / 256, 256, 0, stream>>>(ei, lastidx, counts);
    prep_w_kernel<<<18 * 64, 256, 0, stream>>>(lin_w, k_w, q_w, v_w, a_w, rel_att, rel_msg,
                                               wTall, flag);
    prep_misc_kernel<<<18, 128, 0, stream>>>(lin_b, k_b, q_b, v_b, a_b, rel_att, rel_msg,
                                             rel_p, skip, biasall, relpf, skipf, flag);
    scan1_kernel<<<NE * NCHUNK, 256, 0, stream>>>(counts, offs, bsum);
    scan2_kernel<<<NE, 256, 0, stream>>>(bsum);
    scan3_kernel<<<NE * NCHUNK, 256, 0, stream>>>(offs, bsum, cursor);
    fill_kernel<<<(NE * NEDGE + 255) / 256, 256, 0, stream>>>(ei, cursor, srcb);
    ewsc_kernel<<<(NT * NN + 255) / 256, 256, 0, stream>>>(ew, lastidx, ewsc, flag);

    lin_gemm<<<NT * MBLK64, 256, 0, stream>>>(x, wTall, biasall, ewsc, h, flag);

    for (int l = 0; l < NL; l++) {
        kqv_gemm<<<NT * MBLK64, 256, 0, stream>>>(h, wTall, biasall, l, kk, qq, vv);
        agg_kernel<<<NE * AGGB, 256, 0, stream>>>(qq, kk, vv, srcb, offs, relpf, l, aggb);
        outproj_gemm<<<NT * MBLK64, 256, 0, stream>>>(aggb, wTall, biasall, skipf, l, h,
                                                      (l == NL - 1) ? 1 : 0, d_out, flag);
    }
}

// Round 7
// 535.781 us; speedup vs baseline: 2.7523x; 1.0642x over previous
//
#include <hip/hip_runtime.h>
#include <hip/hip_bf16.h>
#include <math.h>

typedef __hip_bfloat16 bf16;
typedef _Float16 f16;
typedef __attribute__((ext_vector_type(2))) _Float16 f16x2;
typedef __attribute__((ext_vector_type(8))) short bf16x8;   // MFMA A/B frag (4 VGPRs)
typedef __attribute__((ext_vector_type(4))) float f32x4;    // MFMA C/D frag

#define NT 2
#define NE 2
#define NN 50000
#define HID 128
#define NH 4
#define DD 32
#define NL 2
#define NEDGE 400000
#define NCHUNK 196      // ceil(50000/256)
#define MBLK64 782      // ceil(50000/64)
#define AGGB 12500      // NN/4 (one wave per dst, 4 waves/block)
#define WPITCH 136      // LDS W row pitch (elems): 272 B, 16B-aligned, 2-way banks (free)

__device__ __forceinline__ float b2f(bf16 v) { return __bfloat162float(v); }
__device__ __forceinline__ float toF(float v) { return v; }
__device__ __forceinline__ float toF(bf16 v) { return b2f(v); }
__device__ __forceinline__ float sigm(float x) { return 1.0f / (1.0f + __expf(-x)); }
__device__ __forceinline__ unsigned short f2bits(float f) {
    bf16 h = __float2bfloat16(f);
    unsigned short b; __builtin_memcpy(&b, &h, 2); return b;
}
__device__ __forceinline__ float bits2f(unsigned short b) {
    unsigned u = ((unsigned)b) << 16; float f; __builtin_memcpy(&f, &u, 4); return f;
}
__device__ __forceinline__ unsigned short f2hbits(float f) {
    f16 h = (f16)f;
    unsigned short b; __builtin_memcpy(&b, &h, 2); return b;
}

__device__ __forceinline__ float dot8_f16(const unsigned* kr, const f16x2 q[4], float init) {
    float p = init;
#pragma unroll
    for (int i = 0; i < 4; i++) {
        f16x2 kh; __builtin_memcpy(&kh, &kr[i], 4);
#if __has_builtin(__builtin_amdgcn_fdot2)
        p = __builtin_amdgcn_fdot2(q[i], kh, p, false);
#else
        p += (float)q[i].x * (float)kh.x + (float)q[i].y * (float)kh.y;
#endif
    }
    return p;
}

// ---- input dtype detection (0 = bf16, 1 = fp32) -----------------------------
__global__ void detect_kernel(const void* __restrict__ x, int* __restrict__ flag) {
    int lane = threadIdx.x;  // 64
    const unsigned short* u = (const unsigned short*)x;
    int cnt = 0;
    for (int i = 0; i < 4; i++) {
        unsigned short w = u[lane * 4 + i];
        int e = (w >> 7) & 0xFF;
        if (e >= 110 && e <= 135) cnt++;
    }
    for (int off = 32; off > 0; off >>= 1) cnt += __shfl_xor(cnt, off, 64);
    if (lane == 0) *flag = (cnt > 200) ? 0 : 1;
}

// ---- merged last-edge-index + dst-degree count ------------------------------
__global__ void lastcnt_kernel(const int* __restrict__ ei, int* __restrict__ lastidx,
                               int* __restrict__ counts) {
    int idx = blockIdx.x * blockDim.x + threadIdx.x;
    if (idx >= NE * NEDGE) return;
    int e = idx / NEDGE, j = idx % NEDGE;
    int src = ei[(e * 2 + 0) * NEDGE + j];   // EDGE_SRC=(0,1): src type == e
    int dst = ei[(e * 2 + 1) * NEDGE + j];
    atomicMax(&lastidx[e * NN + src], j);
    atomicAdd(&counts[e * NN + dst], 1);
}

// ---- CSR scans --------------------------------------------------------------
__global__ void scan1_kernel(const int* __restrict__ counts, int* __restrict__ offs,
                             int* __restrict__ bsum) {
    int e = blockIdx.x / NCHUNK, cb = blockIdx.x % NCHUNK;
    int tid = threadIdx.x;
    int idx = cb * 256 + tid;
    int v = (idx < NN) ? counts[e * NN + idx] : 0;
    __shared__ int sb[256];
    sb[tid] = v; __syncthreads();
    for (int off = 1; off < 256; off <<= 1) {
        int a = (tid >= off) ? sb[tid - off] : 0;
        __syncthreads();
        sb[tid] += a;
        __syncthreads();
    }
    if (idx < NN) offs[e * (NN + 1) + idx] = sb[tid] - v;
    if (tid == 255) bsum[e * NCHUNK + cb] = sb[255];
}

__global__ void scan2_kernel(int* __restrict__ bsum) {
    int e = blockIdx.x;
    int tid = threadIdx.x;
    int v = (tid < NCHUNK) ? bsum[e * NCHUNK + tid] : 0;
    __shared__ int sb[256];
    sb[tid] = v; __syncthreads();
    for (int off = 1; off < 256; off <<= 1) {
        int a = (tid >= off) ? sb[tid - off] : 0;
        __syncthreads();
        sb[tid] += a;
        __syncthreads();
    }
    if (tid < NCHUNK) bsum[e * NCHUNK + tid] = sb[tid] - v;
}

__global__ void scan3_kernel(int* __restrict__ offs, const int* __restrict__ bsum,
                             int* __restrict__ cursor) {
    int e = blockIdx.x / NCHUNK, cb = blockIdx.x % NCHUNK;
    int idx = cb * 256 + threadIdx.x;
    if (idx < NN) {
        int v = offs[e * (NN + 1) + idx] + bsum[e * NCHUNK + cb];
        offs[e * (NN + 1) + idx] = v;
        cursor[e * NN + idx] = v;
    } else if (idx == NN) {
        offs[e * (NN + 1) + NN] = NEDGE;
    }
}

__global__ void fill_kernel(const int* __restrict__ ei, int* __restrict__ cursor,
                            int* __restrict__ srcb) {
    int idx = blockIdx.x * blockDim.x + threadIdx.x;
    if (idx >= NE * NEDGE) return;
    int e = idx / NEDGE, j = idx % NEDGE;
    int src = ei[(e * 2 + 0) * NEDGE + j];
    int dst = ei[(e * 2 + 1) * NEDGE + j];
    int pos = atomicAdd(&cursor[e * NN + dst], 1);
    srcb[e * NEDGE + pos] = src;
}

// ---- per-node sigmoid(ew[last]) scale ---------------------------------------
template <typename T>
__device__ __forceinline__ void ewsc_body(const T* __restrict__ ew, const int* __restrict__ lastidx,
                                          float* __restrict__ ewsc) {
    int idx = blockIdx.x * blockDim.x + threadIdx.x;
    if (idx >= NT * NN) return;
    int t = idx / NN;
    int li = lastidx[idx];
    ewsc[idx] = (li >= 0) ? sigm(toF(ew[(size_t)t * NEDGE + li])) : 1.0f;
}
__global__ void ewsc_kernel(const void* ew, const int* lastidx, float* ewsc, const int* flag) {
    if (*flag) ewsc_body<float>((const float*)ew, lastidx, ewsc);
    else       ewsc_body<bf16>((const bf16*)ew, lastidx, ewsc);
}

// ---- weight prep: transpose + fold rel into K/V weights ---------------------
// wT layout (bf16, [n][k]): mat 0,1 = linT; mat 2+lt*3+{0,1,2} = kT_fold,qT,vT_fold
// (lt = l*2+t); mat 14+lt = aT.
template <typename T>
__device__ __forceinline__ void prep_w_body(const T* lin_w, const T* k_w, const T* q_w,
                                            const T* v_w, const T* a_w, const T* rel_att,
                                            const T* rel_msg, unsigned short* wT) {
    int bid = blockIdx.x, tid = threadIdx.x;
    int mat = bid >> 6;
    int elem = (bid & 63) * 256 + tid;
    int n = elem >> 7, k = elem & 127;
    float v;
    if (mat < 2) {
        v = toF(lin_w[(size_t)mat * 16384 + k * 128 + n]);
    } else if (mat < 14) {
        int m2 = mat - 2, lt = m2 / 3, op = m2 % 3;
        if (op == 1) {
            v = toF(q_w[(size_t)lt * 16384 + k * 128 + n]);
        } else {
            const T* w = (op == 0 ? k_w : v_w) + (size_t)lt * 16384 + k * 128;
            const T* rl = (op == 0 ? rel_att : rel_msg) + (size_t)lt * 4096;  // e == t
            int hh = n >> 5, jj = n & 31;
            float s = 0.f;
#pragma unroll 8
            for (int d = 0; d < 32; d++)
                s += toF(w[hh * 32 + d]) * toF(rl[(hh * 32 + d) * 32 + jj]);
            v = s;
        }
    } else {
        v = toF(a_w[(size_t)(mat - 14) * 16384 + k * 128 + n]);
    }
    wT[(size_t)mat * 16384 + n * 128 + k] = f2bits(v);
}
__global__ void prep_w_kernel(const void* lin_w, const void* k_w, const void* q_w,
                              const void* v_w, const void* a_w, const void* rel_att,
                              const void* rel_msg, unsigned short* wT, const int* flag) {
    if (*flag) prep_w_body<float>((const float*)lin_w, (const float*)k_w, (const float*)q_w,
                                  (const float*)v_w, (const float*)a_w, (const float*)rel_att,
                                  (const float*)rel_msg, wT);
    else       prep_w_body<bf16>((const bf16*)lin_w, (const bf16*)k_w, (const bf16*)q_w,
                                 (const bf16*)v_w, (const bf16*)a_w, (const bf16*)rel_att,
                                 (const bf16*)rel_msg, wT);
}

// ---- bias prep (fp32) + rel_p + skip ----------------------------------------
template <typename T>
__device__ __forceinline__ void prep_misc_body(const T* lin_b, const T* k_b, const T* q_b,
                                               const T* v_b, const T* a_b, const T* rel_att,
                                               const T* rel_msg, const T* rel_p, const T* skip,
                                               float* biasall, float* relpf, float* skipf) {
    int mat = blockIdx.x, n = threadIdx.x;  // 18 x 128
    float v;
    if (mat < 2) {
        v = toF(lin_b[mat * 128 + n]);
    } else if (mat < 14) {
        int m2 = mat - 2, lt = m2 / 3, op = m2 % 3;
        if (op == 1) {
            v = toF(q_b[lt * 128 + n]);
        } else {
            const T* b = (op == 0 ? k_b : v_b) + lt * 128;
            const T* rl = (op == 0 ? rel_att : rel_msg) + (size_t)lt * 4096;
            int hh = n >> 5, jj = n & 31;
            float s = 0.f;
#pragma unroll 8
            for (int d = 0; d < 32; d++)
                s += toF(b[hh * 32 + d]) * toF(rl[(hh * 32 + d) * 32 + jj]);
            v = s;
        }
    } else {
        v = toF(a_b[(mat - 14) * 128 + n]);
    }
    biasall[mat * 128 + n] = v;
    if (mat == 0 && n < 16) relpf[n] = toF(rel_p[n]);
    if (mat == 1 && n < 4) skipf[n] = toF(skip[n]);
}
__global__ void prep_misc_kernel(const void* lin_b, const void* k_b, const void* q_b,
                                 const void* v_b, const void* a_b, const void* rel_att,
                                 const void* rel_msg, const void* rel_p, const void* skip,
                                 float* biasall, float* relpf, float* skipf, const int* flag) {
    if (*flag) prep_misc_body<float>((const float*)lin_b, (const float*)k_b, (const float*)q_b,
                                     (const float*)v_b, (const float*)a_b, (const float*)rel_att,
                                     (const float*)rel_msg, (const float*)rel_p, (const float*)skip,
                                     biasall, relpf, skipf);
    else       prep_misc_body<bf16>((const bf16*)lin_b, (const bf16*)k_b, (const bf16*)q_b,
                                    (const bf16*)v_b, (const bf16*)a_b, (const bf16*)rel_att,
                                    (const bf16*)rel_msg, (const bf16*)rel_p, (const bf16*)skip,
                                    biasall, relpf, skipf);
}

// ---- shared GEMM helpers ----------------------------------------------------
__device__ __forceinline__ void stage_w(unsigned short* __restrict__ Wl,
                                        const unsigned short* __restrict__ wmat, int tid) {
#pragma unroll
    for (int i = 0; i < 8; i++) {
        int c = i * 256 + tid;           // 2048 chunks of 8
        int n = c >> 4, ko = (c & 15) * 8;
        *(bf16x8*)&Wl[n * WPITCH + ko] = *(const bf16x8*)&wmat[n * 128 + ko];
    }
}

__device__ __forceinline__ void mfma_pass(const unsigned short* __restrict__ Wl,
                                          const bf16x8 af[4], const float* __restrict__ bias,
                                          f32x4 acc[8], int m16, int quad) {
#pragma unroll
    for (int ni = 0; ni < 8; ni++) {
        float b = bias[ni * 16 + m16];
        f32x4 iv = {b, b, b, b};
        acc[ni] = iv;
    }
#pragma unroll
    for (int ks = 0; ks < 4; ks++) {
        bf16x8 a = af[ks];
#pragma unroll
        for (int ni = 0; ni < 8; ni++) {
            bf16x8 bb = *(const bf16x8*)&Wl[(ni * 16 + m16) * WPITCH + ks * 32 + quad * 8];
            acc[ni] = __builtin_amdgcn_mfma_f32_16x16x32_bf16(a, bb, acc[ni], 0, 0, 0);
        }
    }
}

// ---- lin: x -> h = relu(x W + b) * ewsc  (h fp32) ---------------------------
template <bool FP32>
__device__ __forceinline__ void lin_body(const void* __restrict__ x,
                                         const unsigned short* __restrict__ wT,
                                         const float* __restrict__ biasall,
                                         const float* __restrict__ ewsc,
                                         float* __restrict__ h) {
    __shared__ unsigned short Wl[128 * WPITCH];
    int bid = blockIdx.x, tid = threadIdx.x;
    int t = bid / MBLK64, nb = (bid % MBLK64) * 64;
    int wave = tid >> 6, lane = tid & 63;
    int m16 = lane & 15, quad = lane >> 4;
    stage_w(Wl, wT + (size_t)t * 16384, tid);
    int arow = nb + wave * 16 + m16;
    int arc = arow < NN ? arow : NN - 1;
    size_t abase = ((size_t)t * NN + arc) * 128;
    bf16x8 af[4];
#pragma unroll
    for (int ks = 0; ks < 4; ks++) {
        if (FP32) {
            const float4* s = (const float4*)((const float*)x + abase + ks * 32 + quad * 8);
            float4 f0 = s[0], f1 = s[1];
            unsigned short* pu = (unsigned short*)&af[ks];
            pu[0] = f2bits(f0.x); pu[1] = f2bits(f0.y); pu[2] = f2bits(f0.z); pu[3] = f2bits(f0.w);
            pu[4] = f2bits(f1.x); pu[5] = f2bits(f1.y); pu[6] = f2bits(f1.z); pu[7] = f2bits(f1.w);
        } else {
            af[ks] = *(const bf16x8*)((const unsigned short*)x + abase + ks * 32 + quad * 8);
        }
    }
    __syncthreads();
    f32x4 acc[8];
    mfma_pass(Wl, af, biasall + t * 128, acc, m16, quad);
#pragma unroll
    for (int r = 0; r < 4; r++) {
        int node = nb + wave * 16 + quad * 4 + r;
        if (node < NN) {
            float es = ewsc[t * NN + node];
            size_t ro = ((size_t)t * NN + node) * 128;
#pragma unroll
            for (int ni = 0; ni < 8; ni++)
                h[ro + ni * 16 + m16] = fmaxf(acc[ni][r], 0.f) * es;
        }
    }
}
__global__ void __launch_bounds__(256, 4) lin_gemm(const void* x, const unsigned short* wT,
                                                   const float* biasall, const float* ewsc,
                                                   float* h, const int* flag) {
    if (*flag) lin_body<true>(x, wT, biasall, ewsc, h);
    else       lin_body<false>(x, wT, biasall, ewsc, h);
}

// ---- kqv: h -> k_rel / q / v_rel (all fp16); rel folded into W --------------
__global__ void __launch_bounds__(256, 4) kqv_gemm(const float* __restrict__ h,
                                                   const unsigned short* __restrict__ wTall,
                                                   const float* __restrict__ biasall, int l,
                                                   unsigned short* __restrict__ kk,
                                                   unsigned short* __restrict__ qq,
                                                   unsigned short* __restrict__ vv) {
    __shared__ unsigned short Wl[128 * WPITCH];
    int bid = blockIdx.x, tid = threadIdx.x;
    int t = bid / MBLK64, nb = (bid % MBLK64) * 64;
    int lt = l * 2 + t;
    int wave = tid >> 6, lane = tid & 63;
    int m16 = lane & 15, quad = lane >> 4;
    int arow = nb + wave * 16 + m16;
    int arc = arow < NN ? arow : NN - 1;
    size_t abase = ((size_t)t * NN + arc) * 128;
    bf16x8 af[4];
#pragma unroll
    for (int ks = 0; ks < 4; ks++) {
        const float4* s = (const float4*)(h + abase + ks * 32 + quad * 8);
        float4 f0 = s[0], f1 = s[1];
        unsigned short* pu = (unsigned short*)&af[ks];
        pu[0] = f2bits(f0.x); pu[1] = f2bits(f0.y); pu[2] = f2bits(f0.z); pu[3] = f2bits(f0.w);
        pu[4] = f2bits(f1.x); pu[5] = f2bits(f1.y); pu[6] = f2bits(f1.z); pu[7] = f2bits(f1.w);
    }
    f32x4 acc[8];
#pragma unroll
    for (int pass = 0; pass < 3; pass++) {
        int mat = 2 + lt * 3 + pass;
        __syncthreads();   // prior pass's MFMA reads done before restaging W
        stage_w(Wl, wTall + (size_t)mat * 16384, tid);
        __syncthreads();
        mfma_pass(Wl, af, biasall + mat * 128, acc, m16, quad);
        unsigned short* dst = (pass == 0) ? kk : (pass == 1 ? qq : vv);
#pragma unroll
        for (int r = 0; r < 4; r++) {
            int node = nb + wave * 16 + quad * 4 + r;
            if (node < NN) {
                size_t ro = ((size_t)t * NN + node) * 128;
#pragma unroll
                for (int ni = 0; ni < 8; ni++)
                    dst[ro + ni * 16 + m16] = f2hbits(acc[ni][r]);
            }
        }
    }
}

// ---- merged-edge-type segment-softmax aggregation ---------------------------
// 1 wave per dst; 4 streams of 16 lanes; 8 fp16 chans/lane. Weights are raw
// exp2(score*log2e) (no max subtraction -- exact softmax ratios, fp32-safe for
// |score|<88). aggb (bf16) aliases qq (fp16): each row read by its own wave
// before that wave writes it; rows disjoint across waves.
__global__ void __launch_bounds__(256) agg_kernel(const unsigned short* __restrict__ qq,
                                                  const unsigned short* __restrict__ kk,
                                                  const unsigned short* __restrict__ vv,
                                                  const int* __restrict__ srcb,
                                                  const int* __restrict__ offs,
                                                  const float* __restrict__ relpf, int l,
                                                  unsigned short* __restrict__ aggb) {
    int bid = blockIdx.x;
    int e = bid / AGGB;
    int wave = threadIdx.x >> 6, lane = threadIdx.x & 63;
    int dst = (bid % AGGB) * 4 + wave;
    int t = 1 - e;                      // EDGE_DST=(1,0)
    int le = l * 2 + e;
    int stream = lane >> 4, l4 = lane & 15;
    int c0 = l4 * 8, head = l4 >> 2;
    const int* offs_e = offs + e * (NN + 1);
    const int* srcb_e = srcb + (size_t)e * NEDGE;
    int beg = offs_e[dst], end = offs_e[dst + 1];
    size_t rowo = ((size_t)t * NN + dst) * 128 + c0;
    // log2e folded into scale; exp2f == v_exp_f32 native
    float scale = relpf[le * 4 + head] * 0.17677669529663687f * 1.44269504088896f;
    uint4 qraw = *(const uint4*)&qq[rowo];
    f16x2 q[4];
    __builtin_memcpy(&q[0], &qraw.x, 4); __builtin_memcpy(&q[1], &qraw.y, 4);
    __builtin_memcpy(&q[2], &qraw.z, 4); __builtin_memcpy(&q[3], &qraw.w, 4);
    const unsigned short* kb = kk + (size_t)e * NN * 128;   // EDGE_SRC=(0,1): s == e
    const unsigned short* vb = vv + (size_t)e * NN * 128;
    float lsum = 0.f;
    float acc[8] = {0.f, 0.f, 0.f, 0.f, 0.f, 0.f, 0.f, 0.f};
    for (int j = beg + stream; j < end; j += 4) {
        int src = srcb_e[j];
        size_t so = (size_t)src * 128 + c0;
        uint4 kraw = *(const uint4*)&kb[so];
        uint4 vraw = *(const uint4*)&vb[so];
        float p = dot8_f16((const unsigned*)&kraw, q, 0.f);
        p += __shfl_xor(p, 1, 64);      // reduce 4 lanes = 32 chans = one head
        p += __shfl_xor(p, 2, 64);
        float es = exp2f(p * scale);
        lsum += es;
        const unsigned* vr = (const unsigned*)&vraw;
#pragma unroll
        for (int i = 0; i < 4; i++) {
            f16x2 vh; __builtin_memcpy(&vh, &vr[i], 4);
            acc[i * 2]     += es * (float)vh.x;
            acc[i * 2 + 1] += es * (float)vh.y;
        }
    }
    // sum across the 4 streams (same chans at lane^16, lane^32)
    lsum += __shfl_xor(lsum, 16, 64);
#pragma unroll
    for (int i = 0; i < 8; i++) acc[i] += __shfl_xor(acc[i], 16, 64);
    lsum += __shfl_xor(lsum, 32, 64);
#pragma unroll
    for (int i = 0; i < 8; i++) acc[i] += __shfl_xor(acc[i], 32, 64);
    if (stream == 0) {
        float inv = 1.0f / (lsum + 1e-16f);
        unsigned short o[8];
#pragma unroll
        for (int i = 0; i < 8; i++) o[i] = f2bits(acc[i] * inv);
        *(bf16x8*)&aggb[rowo] = *(bf16x8*)o;
    }
}

// ---- outproj: h' = beta*(gelu(agg) W_a + b_a) + (1-beta)*h; final -> out ----
__global__ void __launch_bounds__(256, 4) outproj_gemm(const unsigned short* __restrict__ aggb,
                                                       const unsigned short* __restrict__ wTall,
                                                       const float* __restrict__ biasall,
                                                       const float* __restrict__ skipf, int l,
                                                       float* __restrict__ h, int last,
                                                       void* __restrict__ outp,
                                                       const int* __restrict__ flag) {
    __shared__ unsigned short Wl[128 * WPITCH];
    int bid = blockIdx.x, tid = threadIdx.x;
    int t = bid / MBLK64, nb = (bid % MBLK64) * 64;
    int lt = l * 2 + t;
    int wave = tid >> 6, lane = tid & 63;
    int m16 = lane & 15, quad = lane >> 4;
    int mat = 14 + lt;
    stage_w(Wl, wTall + (size_t)mat * 16384, tid);
    int arow = nb + wave * 16 + m16;
    int arc = arow < NN ? arow : NN - 1;
    size_t abase = ((size_t)t * NN + arc) * 128;
    bf16x8 af[4];
#pragma unroll
    for (int ks = 0; ks < 4; ks++) {
        bf16x8 raw = *(const bf16x8*)&aggb[abase + ks * 32 + quad * 8];
        const unsigned short* ru = (const unsigned short*)&raw;
        unsigned short* pu = (unsigned short*)&af[ks];
#pragma unroll
        for (int jj = 0; jj < 8; jj++) {
            float g = bits2f(ru[jj]);
            pu[jj] = f2bits(0.5f * g * (1.0f + erff(g * 0.70710678118654752f)));  // exact gelu
        }
    }
    __syncthreads();
    f32x4 acc[8];
    mfma_pass(Wl, af, biasall + mat * 128, acc, m16, quad);
    float beta = sigm(skipf[lt]);
    int fl = *flag;
#pragma unroll
    for (int r = 0; r < 4; r++) {
        int node = nb + wave * 16 + quad * 4 + r;
        if (node < NN) {
            size_t ro = ((size_t)t * NN + node) * 128;
#pragma unroll
            for (int ni = 0; ni < 8; ni++) {
                size_t io = ro + ni * 16 + m16;
                float nv = beta * acc[ni][r] + (1.0f - beta) * h[io];
                h[io] = nv;
                if (last) {
                    if (fl) ((float*)outp)[io] = nv;
                    else    ((bf16*)outp)[io] = __float2bfloat16(nv);
                }
            }
        }
    }
}

extern "C" void kernel_launch(void* const* d_in, const int* in_sizes, int n_in,
                              void* d_out, int out_size, void* d_ws, size_t ws_size,
                              hipStream_t stream) {
    const void* x      = d_in[0];
    const int*  ei     = (const int*)d_in[1];
    const void* ew     = d_in[2];
    const void* lin_w  = d_in[3];
    const void* lin_b  = d_in[4];
    const void* k_w    = d_in[5];
    const void* k_b    = d_in[6];
    const void* q_w    = d_in[7];
    const void* q_b    = d_in[8];
    const void* v_w    = d_in[9];
    const void* v_b    = d_in[10];
    const void* a_w    = d_in[11];
    const void* a_b    = d_in[12];
    const void* skip   = d_in[13];
    const void* rel_att = d_in[14];
    const void* rel_msg = d_in[15];
    const void* rel_p  = d_in[16];

    char* p = (char*)d_ws;
    auto alloc = [&](size_t bytes) -> char* {
        char* r = p;
        p += (bytes + 255) & ~(size_t)255;
        return r;
    };
    int* flag     = (int*)alloc(sizeof(int));
    int* counts   = (int*)alloc(sizeof(int) * NE * NN);
    int* offs     = (int*)alloc(sizeof(int) * NE * (NN + 1));
    int* bsum     = (int*)alloc(sizeof(int) * NE * NCHUNK);
    int* cursor   = (int*)alloc(sizeof(int) * NE * NN);
    int* srcb     = (int*)alloc(sizeof(int) * NE * NEDGE);
    int* lastidx  = (int*)alloc(sizeof(int) * NT * NN);
    unsigned short* wTall = (unsigned short*)alloc(sizeof(short) * 18 * 16384);
    float* biasall = (float*)alloc(sizeof(float) * 18 * 128);
    float* relpf   = (float*)alloc(sizeof(float) * 16);
    float* skipf   = (float*)alloc(sizeof(float) * 4);
    float* ewsc    = (float*)alloc(sizeof(float) * NT * NN);
    float* h       = (float*)alloc(sizeof(float) * NT * NN * HID);               // 51.2 MB fp32
    unsigned short* qq = (unsigned short*)alloc(sizeof(short) * NT * NN * HID);  // fp16 (aggb aliases, bf16)
    unsigned short* kk = (unsigned short*)alloc(sizeof(short) * NT * NN * HID);  // fp16
    unsigned short* vv = (unsigned short*)alloc(sizeof(short) * NT * NN * HID);  // fp16
    unsigned short* aggb = qq;

    hipMemsetAsync(lastidx, 0xFF, sizeof(int) * NT * NN, stream);
    hipMemsetAsync(counts, 0, sizeof(int) * NE * NN, stream);

    detect_kernel<<<1, 64, 0, stream>>>(x, flag);
    lastcnt_kernel<<<(NE * NEDGE + 255) / 256, 256, 0, stream>>>(ei, lastidx, counts);
    prep_w_kernel<<<18 * 64, 256, 0, stream>>>(lin_w, k_w, q_w, v_w, a_w, rel_att, rel_msg,
                                               wTall, flag);
    prep_misc_kernel<<<18, 128, 0, stream>>>(lin_b, k_b, q_b, v_b, a_b, rel_att, rel_msg,
                                             rel_p, skip, biasall, relpf, skipf, flag);
    scan1_kernel<<<NE * NCHUNK, 256, 0, stream>>>(counts, offs, bsum);
    scan2_kernel<<<NE, 256, 0, stream>>>(bsum);
    scan3_kernel<<<NE * NCHUNK, 256, 0, stream>>>(offs, bsum, cursor);
    fill_kernel<<<(NE * NEDGE + 255) / 256, 256, 0, stream>>>(ei, cursor, srcb);
    ewsc_kernel<<<(NT * NN + 255) / 256, 256, 0, stream>>>(ew, lastidx, ewsc, flag);

    lin_gemm<<<NT * MBLK64, 256, 0, stream>>>(x, wTall, biasall, ewsc, h, flag);

    for (int l = 0; l < NL; l++) {
        kqv_gemm<<<NT * MBLK64, 256, 0, stream>>>(h, wTall, biasall, l, kk, qq, vv);
        agg_kernel<<<NE * AGGB, 256, 0, stream>>>(qq, kk, vv, srcb, offs, relpf, l, aggb);
        outproj_gemm<<<NT * MBLK64, 256, 0, stream>>>(aggb, wTall, biasall, skipf, l, h,
                                                      (l == NL - 1) ? 1 : 0, d_out, flag);
    }
}

// Round 8
// 451.335 us; speedup vs baseline: 3.2672x; 1.1871x over previous
//
#include <hip/hip_runtime.h>
#include <hip/hip_bf16.h>
#include <math.h>

typedef __hip_bfloat16 bf16;
typedef _Float16 f16;
typedef __attribute__((ext_vector_type(2))) _Float16 f16x2;
typedef __attribute__((ext_vector_type(8))) short bf16x8;   // MFMA A/B frag (4 VGPRs)
typedef __attribute__((ext_vector_type(4))) float f32x4;    // MFMA C/D frag

#define NT 2
#define NE 2
#define NN 50000
#define HID 128
#define NH 4
#define DD 32
#define NL 2
#define NEDGE 400000
#define MBLK64 782      // ceil(50000/64)
#define AGGB 12500      // NN/4 (one wave per dst, 4 waves/block)
#define WPITCH 136      // LDS W row pitch (elems): 272 B, 16B-aligned, 2-way banks (free)
#define CB 196          // coarse buckets (key >> 8), covers 50176 nodes
#define CAP 4096        // bucket capacity (expected 2040, +45 sigma margin)
#define CHUNK 2048      // edges per bucket1 block
#define NCH 196         // ceil(NEDGE / CHUNK)

__device__ __forceinline__ float b2f(bf16 v) { return __bfloat162float(v); }
__device__ __forceinline__ float toF(float v) { return v; }
__device__ __forceinline__ float toF(bf16 v) { return b2f(v); }
__device__ __forceinline__ float sigm(float x) { return 1.0f / (1.0f + __expf(-x)); }
__device__ __forceinline__ unsigned short f2bits(float f) {
    bf16 h = __float2bfloat16(f);
    unsigned short b; __builtin_memcpy(&b, &h, 2); return b;
}
__device__ __forceinline__ float bits2f(unsigned short b) {
    unsigned u = ((unsigned)b) << 16; float f; __builtin_memcpy(&f, &u, 4); return f;
}
__device__ __forceinline__ unsigned short f2hbits(float f) {
    f16 h = (f16)f;
    unsigned short b; __builtin_memcpy(&b, &h, 2); return b;
}

__device__ __forceinline__ float dot8_f16(const unsigned* kr, const f16x2 q[4], float init) {
    float p = init;
#pragma unroll
    for (int i = 0; i < 4; i++) {
        f16x2 kh; __builtin_memcpy(&kh, &kr[i], 4);
#if __has_builtin(__builtin_amdgcn_fdot2)
        p = __builtin_amdgcn_fdot2(q[i], kh, p, false);
#else
        p += (float)q[i].x * (float)kh.x + (float)q[i].y * (float)kh.y;
#endif
    }
    return p;
}

// ---- input dtype detection (0 = bf16, 1 = fp32) -----------------------------
__global__ void detect_kernel(const void* __restrict__ x, int* __restrict__ flag) {
    int lane = threadIdx.x;  // 64
    const unsigned short* u = (const unsigned short*)x;
    int cnt = 0;
    for (int i = 0; i < 4; i++) {
        unsigned short w = u[lane * 4 + i];
        int e = (w >> 7) & 0xFF;
        if (e >= 110 && e <= 135) cnt++;
    }
    for (int off = 32; off > 0; off >>= 1) cnt += __shfl_xor(cnt, off, 64);
    if (lane == 0) *flag = (cnt > 200) ? 0 : 1;
}

// ---- coarse bucketing: one edge pass, dst-keyed + src-keyed -----------------
// bufd record: (dst&255)<<24 | src  (src < 2^17).
// bufs record: (src&255)<<19 | j    (j < 2^19).
// Global atomics: one per nonempty (block, bin) -- ~80k total vs 2.4M before.
__global__ void bucket1_kernel(const int* __restrict__ ei, int* __restrict__ gcd,
                               int* __restrict__ gcs, unsigned* __restrict__ bufd,
                               unsigned* __restrict__ bufs) {
    int blk = blockIdx.x;               // NE * NCH
    int e = blk / NCH, ch = blk % NCH;
    int tid = threadIdx.x;              // 256
    __shared__ int hd[CB], hs[CB], bd[CB], bs[CB];
    for (int i = tid; i < CB; i += 256) { hd[i] = 0; hs[i] = 0; }
    __syncthreads();
    const int* srcp = ei + (e * 2 + 0) * NEDGE;
    const int* dstp = ei + (e * 2 + 1) * NEDGE;
    int j0 = ch * CHUNK;
    int src[8], dst[8], rd[8], rs[8];
#pragma unroll
    for (int i = 0; i < 8; i++) {
        int j = j0 + i * 256 + tid;
        if (j < NEDGE) {
            src[i] = srcp[j]; dst[i] = dstp[j];
            rd[i] = atomicAdd(&hd[dst[i] >> 8], 1);
            rs[i] = atomicAdd(&hs[src[i] >> 8], 1);
        } else src[i] = -1;
    }
    __syncthreads();
    for (int i = tid; i < CB; i += 256) {
        bd[i] = hd[i] ? atomicAdd(&gcd[e * CB + i], hd[i]) : 0;
        bs[i] = hs[i] ? atomicAdd(&gcs[e * CB + i], hs[i]) : 0;
    }
    __syncthreads();
#pragma unroll
    for (int i = 0; i < 8; i++) {
        int j = j0 + i * 256 + tid;
        if (j < NEDGE) {
            int bn = dst[i] >> 8;
            int pd = bd[bn] + rd[i]; if (pd >= CAP) pd = CAP - 1;   // defensive
            bufd[((size_t)e * CB + bn) * CAP + pd] =
                ((unsigned)(dst[i] & 255) << 24) | (unsigned)src[i];
            bn = src[i] >> 8;
            int ps = bs[bn] + rs[i]; if (ps >= CAP) ps = CAP - 1;   // defensive
            bufs[((size_t)e * CB + bn) * CAP + ps] =
                ((unsigned)(src[i] & 255) << 19) | (unsigned)j;
        }
    }
}

// ---- coarse-offset scan (196 bins / edge type) + offs[NN] sentinel ----------
__global__ void cscan_kernel(const int* __restrict__ gcd, int* __restrict__ coff,
                             int* __restrict__ offs) {
    int e = blockIdx.x;                 // NE
    int tid = threadIdx.x;              // 256
    __shared__ int sb[256];
    int v = (tid < CB) ? gcd[e * CB + tid] : 0;
    sb[tid] = v; __syncthreads();
    for (int off = 1; off < 256; off <<= 1) {
        int a = (tid >= off) ? sb[tid - off] : 0;
        __syncthreads();
        sb[tid] += a;
        __syncthreads();
    }
    if (tid < CB) coff[e * (CB + 1) + tid] = sb[tid] - v;   // exclusive
    if (tid == CB - 1) coff[e * (CB + 1) + CB] = sb[tid];
    if (tid == 0) offs[e * (NN + 1) + NN] = NEDGE;
}

// ---- fine pass (dst): per-bucket exact CSR offs + dst-sorted srcb -----------
__global__ void fine_dst_kernel(const unsigned* __restrict__ bufd, const int* __restrict__ gcd,
                                const int* __restrict__ coff, int* __restrict__ offs,
                                int* __restrict__ srcb) {
    int blk = blockIdx.x;               // NE * CB
    int e = blk / CB, bn = blk % CB;
    int tid = threadIdx.x;              // 256
    int cnt = gcd[e * CB + bn]; if (cnt > CAP) cnt = CAP;
    int base = coff[e * (CB + 1) + bn];
    const unsigned* b = bufd + ((size_t)e * CB + bn) * CAP;
    __shared__ int dc[256], ss[256];
    dc[tid] = 0; __syncthreads();
    for (int i = tid; i < cnt; i += 256) atomicAdd(&dc[b[i] >> 24], 1);
    __syncthreads();
    int v = dc[tid];
    ss[tid] = v; __syncthreads();
    for (int off = 1; off < 256; off <<= 1) {
        int a = (tid >= off) ? ss[tid - off] : 0;
        __syncthreads();
        ss[tid] += a;
        __syncthreads();
    }
    int excl = ss[tid] - v;
    int d = bn * 256 + tid;
    if (d < NN) offs[e * (NN + 1) + d] = base + excl;
    dc[tid] = excl;                     // reuse as scatter cursor
    __syncthreads();
    for (int i = tid; i < cnt; i += 256) {
        unsigned w = b[i];
        int r = atomicAdd(&dc[w >> 24], 1);
        srcb[(size_t)e * NEDGE + base + r] = (int)(w & 0xFFFFFF);
    }
}

// ---- fine pass (src): per-src last-edge-index max -> ewsc -------------------
__global__ void fine_src_kernel(const unsigned* __restrict__ bufs, const int* __restrict__ gcs,
                                const void* __restrict__ ew, float* __restrict__ ewsc,
                                const int* __restrict__ flag) {
    int blk = blockIdx.x;               // NE * CB
    int e = blk / CB, bn = blk % CB;
    int tid = threadIdx.x;              // 256
    int cnt = gcs[e * CB + bn]; if (cnt > CAP) cnt = CAP;
    const unsigned* b = bufs + ((size_t)e * CB + bn) * CAP;
    __shared__ int mx[256];
    mx[tid] = -1; __syncthreads();
    for (int i = tid; i < cnt; i += 256) {
        unsigned w = b[i];
        atomicMax(&mx[w >> 19], (int)(w & 0x7FFFF));
    }
    __syncthreads();
    int n = bn * 256 + tid;
    if (n < NN) {
        int mj = mx[tid];
        float v = 1.0f;
        if (mj >= 0)
            v = sigm(*flag ? ((const float*)ew)[(size_t)e * NEDGE + mj]
                           : b2f(((const bf16*)ew)[(size_t)e * NEDGE + mj]));
        ewsc[e * NN + n] = v;           // src type of edge type e == e
    }
}

// ---- weight prep: transpose + fold rel into K/V weights ---------------------
// wT layout (bf16, [n][k]): mat 0,1 = linT; mat 2+lt*3+{0,1,2} = kT_fold,qT,vT_fold
// (lt = l*2+t); mat 14+lt = aT.
template <typename T>
__device__ __forceinline__ void prep_w_body(const T* lin_w, const T* k_w, const T* q_w,
                                            const T* v_w, const T* a_w, const T* rel_att,
                                            const T* rel_msg, unsigned short* wT) {
    int bid = blockIdx.x, tid = threadIdx.x;
    int mat = bid >> 6;
    int elem = (bid & 63) * 256 + tid;
    int n = elem >> 7, k = elem & 127;
    float v;
    if (mat < 2) {
        v = toF(lin_w[(size_t)mat * 16384 + k * 128 + n]);
    } else if (mat < 14) {
        int m2 = mat - 2, lt = m2 / 3, op = m2 % 3;
        if (op == 1) {
            v = toF(q_w[(size_t)lt * 16384 + k * 128 + n]);
        } else {
            const T* w = (op == 0 ? k_w : v_w) + (size_t)lt * 16384 + k * 128;
            const T* rl = (op == 0 ? rel_att : rel_msg) + (size_t)lt * 4096;  // e == t
            int hh = n >> 5, jj = n & 31;
            float s = 0.f;
#pragma unroll 8
            for (int d = 0; d < 32; d++)
                s += toF(w[hh * 32 + d]) * toF(rl[(hh * 32 + d) * 32 + jj]);
            v = s;
        }
    } else {
        v = toF(a_w[(size_t)(mat - 14) * 16384 + k * 128 + n]);
    }
    wT[(size_t)mat * 16384 + n * 128 + k] = f2bits(v);
}
__global__ void prep_w_kernel(const void* lin_w, const void* k_w, const void* q_w,
                              const void* v_w, const void* a_w, const void* rel_att,
                              const void* rel_msg, unsigned short* wT, const int* flag) {
    if (*flag) prep_w_body<float>((const float*)lin_w, (const float*)k_w, (const float*)q_w,
                                  (const float*)v_w, (const float*)a_w, (const float*)rel_att,
                                  (const float*)rel_msg, wT);
    else       prep_w_body<bf16>((const bf16*)lin_w, (const bf16*)k_w, (const bf16*)q_w,
                                 (const bf16*)v_w, (const bf16*)a_w, (const bf16*)rel_att,
                                 (const bf16*)rel_msg, wT);
}

// ---- bias prep (fp32) + rel_p + skip ----------------------------------------
template <typename T>
__device__ __forceinline__ void prep_misc_body(const T* lin_b, const T* k_b, const T* q_b,
                                               const T* v_b, const T* a_b, const T* rel_att,
                                               const T* rel_msg, const T* rel_p, const T* skip,
                                               float* biasall, float* relpf, float* skipf) {
    int mat = blockIdx.x, n = threadIdx.x;  // 18 x 128
    float v;
    if (mat < 2) {
        v = toF(lin_b[mat * 128 + n]);
    } else if (mat < 14) {
        int m2 = mat - 2, lt = m2 / 3, op = m2 % 3;
        if (op == 1) {
            v = toF(q_b[lt * 128 + n]);
        } else {
            const T* b = (op == 0 ? k_b : v_b) + lt * 128;
            const T* rl = (op == 0 ? rel_att : rel_msg) + (size_t)lt * 4096;
            int hh = n >> 5, jj = n & 31;
            float s = 0.f;
#pragma unroll 8
            for (int d = 0; d < 32; d++)
                s += toF(b[hh * 32 + d]) * toF(rl[(hh * 32 + d) * 32 + jj]);
            v = s;
        }
    } else {
        v = toF(a_b[(mat - 14) * 128 + n]);
    }
    biasall[mat * 128 + n] = v;
    if (mat == 0 && n < 16) relpf[n] = toF(rel_p[n]);
    if (mat == 1 && n < 4) skipf[n] = toF(skip[n]);
}
__global__ void prep_misc_kernel(const void* lin_b, const void* k_b, const void* q_b,
                                 const void* v_b, const void* a_b, const void* rel_att,
                                 const void* rel_msg, const void* rel_p, const void* skip,
                                 float* biasall, float* relpf, float* skipf, const int* flag) {
    if (*flag) prep_misc_body<float>((const float*)lin_b, (const float*)k_b, (const float*)q_b,
                                     (const float*)v_b, (const float*)a_b, (const float*)rel_att,
                                     (const float*)rel_msg, (const float*)rel_p, (const float*)skip,
                                     biasall, relpf, skipf);
    else       prep_misc_body<bf16>((const bf16*)lin_b, (const bf16*)k_b, (const bf16*)q_b,
                                    (const bf16*)v_b, (const bf16*)a_b, (const bf16*)rel_att,
                                    (const bf16*)rel_msg, (const bf16*)rel_p, (const bf16*)skip,
                                    biasall, relpf, skipf);
}

// ---- shared GEMM helpers ----------------------------------------------------
__device__ __forceinline__ void stage_w(unsigned short* __restrict__ Wl,
                                        const unsigned short* __restrict__ wmat, int tid) {
#pragma unroll
    for (int i = 0; i < 8; i++) {
        int c = i * 256 + tid;           // 2048 chunks of 8
        int n = c >> 4, ko = (c & 15) * 8;
        *(bf16x8*)&Wl[n * WPITCH + ko] = *(const bf16x8*)&wmat[n * 128 + ko];
    }
}

__device__ __forceinline__ void mfma_pass(const unsigned short* __restrict__ Wl,
                                          const bf16x8 af[4], const float* __restrict__ bias,
                                          f32x4 acc[8], int m16, int quad) {
#pragma unroll
    for (int ni = 0; ni < 8; ni++) {
        float b = bias[ni * 16 + m16];
        f32x4 iv = {b, b, b, b};
        acc[ni] = iv;
    }
#pragma unroll
    for (int ks = 0; ks < 4; ks++) {
        bf16x8 a = af[ks];
#pragma unroll
        for (int ni = 0; ni < 8; ni++) {
            bf16x8 bb = *(const bf16x8*)&Wl[(ni * 16 + m16) * WPITCH + ks * 32 + quad * 8];
            acc[ni] = __builtin_amdgcn_mfma_f32_16x16x32_bf16(a, bb, acc[ni], 0, 0, 0);
        }
    }
}

// ---- lin: x -> h = relu(x W + b) * ewsc  (h fp32) ---------------------------
template <bool FP32>
__device__ __forceinline__ void lin_body(const void* __restrict__ x,
                                         const unsigned short* __restrict__ wT,
                                         const float* __restrict__ biasall,
                                         const float* __restrict__ ewsc,
                                         float* __restrict__ h) {
    __shared__ unsigned short Wl[128 * WPITCH];
    int bid = blockIdx.x, tid = threadIdx.x;
    int t = bid / MBLK64, nb = (bid % MBLK64) * 64;
    int wave = tid >> 6, lane = tid & 63;
    int m16 = lane & 15, quad = lane >> 4;
    stage_w(Wl, wT + (size_t)t * 16384, tid);
    int arow = nb + wave * 16 + m16;
    int arc = arow < NN ? arow : NN - 1;
    size_t abase = ((size_t)t * NN + arc) * 128;
    bf16x8 af[4];
#pragma unroll
    for (int ks = 0; ks < 4; ks++) {
        if (FP32) {
            const float4* s = (const float4*)((const float*)x + abase + ks * 32 + quad * 8);
            float4 f0 = s[0], f1 = s[1];
            unsigned short* pu = (unsigned short*)&af[ks];
            pu[0] = f2bits(f0.x); pu[1] = f2bits(f0.y); pu[2] = f2bits(f0.z); pu[3] = f2bits(f0.w);
            pu[4] = f2bits(f1.x); pu[5] = f2bits(f1.y); pu[6] = f2bits(f1.z); pu[7] = f2bits(f1.w);
        } else {
            af[ks] = *(const bf16x8*)((const unsigned short*)x + abase + ks * 32 + quad * 8);
        }
    }
    __syncthreads();
    f32x4 acc[8];
    mfma_pass(Wl, af, biasall + t * 128, acc, m16, quad);
#pragma unroll
    for (int r = 0; r < 4; r++) {
        int node = nb + wave * 16 + quad * 4 + r;
        if (node < NN) {
            float es = ewsc[t * NN + node];
            size_t ro = ((size_t)t * NN + node) * 128;
#pragma unroll
            for (int ni = 0; ni < 8; ni++)
                h[ro + ni * 16 + m16] = fmaxf(acc[ni][r], 0.f) * es;
        }
    }
}
__global__ void __launch_bounds__(256, 4) lin_gemm(const void* x, const unsigned short* wT,
                                                   const float* biasall, const float* ewsc,
                                                   float* h, const int* flag) {
    if (*flag) lin_body<true>(x, wT, biasall, ewsc, h);
    else       lin_body<false>(x, wT, biasall, ewsc, h);
}

// ---- kqv: h -> k_rel / q / v_rel (all fp16); rel folded into W --------------
__global__ void __launch_bounds__(256, 4) kqv_gemm(const float* __restrict__ h,
                                                   const unsigned short* __restrict__ wTall,
                                                   const float* __restrict__ biasall, int l,
                                                   unsigned short* __restrict__ kk,
                                                   unsigned short* __restrict__ qq,
                                                   unsigned short* __restrict__ vv) {
    __shared__ unsigned short Wl[128 * WPITCH];
    int bid = blockIdx.x, tid = threadIdx.x;
    int t = bid / MBLK64, nb = (bid % MBLK64) * 64;
    int lt = l * 2 + t;
    int wave = tid >> 6, lane = tid & 63;
    int m16 = lane & 15, quad = lane >> 4;
    int arow = nb + wave * 16 + m16;
    int arc = arow < NN ? arow : NN - 1;
    size_t abase = ((size_t)t * NN + arc) * 128;
    bf16x8 af[4];
#pragma unroll
    for (int ks = 0; ks < 4; ks++) {
        const float4* s = (const float4*)(h + abase + ks * 32 + quad * 8);
        float4 f0 = s[0], f1 = s[1];
        unsigned short* pu = (unsigned short*)&af[ks];
        pu[0] = f2bits(f0.x); pu[1] = f2bits(f0.y); pu[2] = f2bits(f0.z); pu[3] = f2bits(f0.w);
        pu[4] = f2bits(f1.x); pu[5] = f2bits(f1.y); pu[6] = f2bits(f1.z); pu[7] = f2bits(f1.w);
    }
    f32x4 acc[8];
#pragma unroll
    for (int pass = 0; pass < 3; pass++) {
        int mat = 2 + lt * 3 + pass;
        __syncthreads();   // prior pass's MFMA reads done before restaging W
        stage_w(Wl, wTall + (size_t)mat * 16384, tid);
        __syncthreads();
        mfma_pass(Wl, af, biasall + mat * 128, acc, m16, quad);
        unsigned short* dst = (pass == 0) ? kk : (pass == 1 ? qq : vv);
#pragma unroll
        for (int r = 0; r < 4; r++) {
            int node = nb + wave * 16 + quad * 4 + r;
            if (node < NN) {
                size_t ro = ((size_t)t * NN + node) * 128;
#pragma unroll
                for (int ni = 0; ni < 8; ni++)
                    dst[ro + ni * 16 + m16] = f2hbits(acc[ni][r]);
            }
        }
    }
}

// ---- merged-edge-type segment-softmax aggregation ---------------------------
// 1 wave per dst; 4 streams of 16 lanes; 8 fp16 chans/lane. Weights are raw
// exp2(score*log2e) (exact softmax ratios, fp32-safe for |score|<88). aggb
// (bf16) aliases qq (fp16): row read by its own wave before the wave writes it.
__global__ void __launch_bounds__(256) agg_kernel(const unsigned short* __restrict__ qq,
                                                  const unsigned short* __restrict__ kk,
                                                  const unsigned short* __restrict__ vv,
                                                  const int* __restrict__ srcb,
                                                  const int* __restrict__ offs,
                                                  const float* __restrict__ relpf, int l,
                                                  unsigned short* __restrict__ aggb) {
    int bid = blockIdx.x;
    int e = bid / AGGB;
    int wave = threadIdx.x >> 6, lane = threadIdx.x & 63;
    int dst = (bid % AGGB) * 4 + wave;
    int t = 1 - e;                      // EDGE_DST=(1,0)
    int le = l * 2 + e;
    int stream = lane >> 4, l4 = lane & 15;
    int c0 = l4 * 8, head = l4 >> 2;
    const int* offs_e = offs + e * (NN + 1);
    const int* srcb_e = srcb + (size_t)e * NEDGE;
    int beg = offs_e[dst], end = offs_e[dst + 1];
    size_t rowo = ((size_t)t * NN + dst) * 128 + c0;
    float scale = relpf[le * 4 + head] * 0.17677669529663687f * 1.44269504088896f;
    uint4 qraw = *(const uint4*)&qq[rowo];
    f16x2 q[4];
    __builtin_memcpy(&q[0], &qraw.x, 4); __builtin_memcpy(&q[1], &qraw.y, 4);
    __builtin_memcpy(&q[2], &qraw.z, 4); __builtin_memcpy(&q[3], &qraw.w, 4);
    const unsigned short* kb = kk + (size_t)e * NN * 128;   // EDGE_SRC=(0,1): s == e
    const unsigned short* vb = vv + (size_t)e * NN * 128;
    float lsum = 0.f;
    float acc[8] = {0.f, 0.f, 0.f, 0.f, 0.f, 0.f, 0.f, 0.f};
    for (int j = beg + stream; j < end; j += 4) {
        int src = srcb_e[j];
        size_t so = (size_t)src * 128 + c0;
        uint4 kraw = *(const uint4*)&kb[so];
        uint4 vraw = *(const uint4*)&vb[so];
        float p = dot8_f16((const unsigned*)&kraw, q, 0.f);
        p += __shfl_xor(p, 1, 64);      // reduce 4 lanes = 32 chans = one head
        p += __shfl_xor(p, 2, 64);
        float es = exp2f(p * scale);
        lsum += es;
        const unsigned* vr = (const unsigned*)&vraw;
#pragma unroll
        for (int i = 0; i < 4; i++) {
            f16x2 vh; __builtin_memcpy(&vh, &vr[i], 4);
            acc[i * 2]     += es * (float)vh.x;
            acc[i * 2 + 1] += es * (float)vh.y;
        }
    }
    lsum += __shfl_xor(lsum, 16, 64);
#pragma unroll
    for (int i = 0; i < 8; i++) acc[i] += __shfl_xor(acc[i], 16, 64);
    lsum += __shfl_xor(lsum, 32, 64);
#pragma unroll
    for (int i = 0; i < 8; i++) acc[i] += __shfl_xor(acc[i], 32, 64);
    if (stream == 0) {
        float inv = 1.0f / (lsum + 1e-16f);
        unsigned short o[8];
#pragma unroll
        for (int i = 0; i < 8; i++) o[i] = f2bits(acc[i] * inv);
        *(bf16x8*)&aggb[rowo] = *(bf16x8*)o;
    }
}

// ---- outproj: h' = beta*(gelu(agg) W_a + b_a) + (1-beta)*h; final -> out ----
__global__ void __launch_bounds__(256, 4) outproj_gemm(const unsigned short* __restrict__ aggb,
                                                       const unsigned short* __restrict__ wTall,
                                                       const float* __restrict__ biasall,
                                                       const float* __restrict__ skipf, int l,
                                                       float* __restrict__ h, int last,
                                                       void* __restrict__ outp,
                                                       const int* __restrict__ flag) {
    __shared__ unsigned short Wl[128 * WPITCH];
    int bid = blockIdx.x, tid = threadIdx.x;
    int t = bid / MBLK64, nb = (bid % MBLK64) * 64;
    int lt = l * 2 + t;
    int wave = tid >> 6, lane = tid & 63;
    int m16 = lane & 15, quad = lane >> 4;
    int mat = 14 + lt;
    stage_w(Wl, wTall + (size_t)mat * 16384, tid);
    int arow = nb + wave * 16 + m16;
    int arc = arow < NN ? arow : NN - 1;
    size_t abase = ((size_t)t * NN + arc) * 128;
    bf16x8 af[4];
#pragma unroll
    for (int ks = 0; ks < 4; ks++) {
        bf16x8 raw = *(const bf16x8*)&aggb[abase + ks * 32 + quad * 8];
        const unsigned short* ru = (const unsigned short*)&raw;
        unsigned short* pu = (unsigned short*)&af[ks];
#pragma unroll
        for (int jj = 0; jj < 8; jj++) {
            float g = bits2f(ru[jj]);
            pu[jj] = f2bits(0.5f * g * (1.0f + erff(g * 0.70710678118654752f)));  // exact gelu
        }
    }
    __syncthreads();
    f32x4 acc[8];
    mfma_pass(Wl, af, biasall + mat * 128, acc, m16, quad);
    float beta = sigm(skipf[lt]);
    int fl = *flag;
#pragma unroll
    for (int r = 0; r < 4; r++) {
        int node = nb + wave * 16 + quad * 4 + r;
        if (node < NN) {
            size_t ro = ((size_t)t * NN + node) * 128;
#pragma unroll
            for (int ni = 0; ni < 8; ni++) {
                size_t io = ro + ni * 16 + m16;
                float nv = beta * acc[ni][r] + (1.0f - beta) * h[io];
                h[io] = nv;
                if (last) {
                    if (fl) ((float*)outp)[io] = nv;
                    else    ((bf16*)outp)[io] = __float2bfloat16(nv);
                }
            }
        }
    }
}

extern "C" void kernel_launch(void* const* d_in, const int* in_sizes, int n_in,
                              void* d_out, int out_size, void* d_ws, size_t ws_size,
                              hipStream_t stream) {
    const void* x      = d_in[0];
    const int*  ei     = (const int*)d_in[1];
    const void* ew     = d_in[2];
    const void* lin_w  = d_in[3];
    const void* lin_b  = d_in[4];
    const void* k_w    = d_in[5];
    const void* k_b    = d_in[6];
    const void* q_w    = d_in[7];
    const void* q_b    = d_in[8];
    const void* v_w    = d_in[9];
    const void* v_b    = d_in[10];
    const void* a_w    = d_in[11];
    const void* a_b    = d_in[12];
    const void* skip   = d_in[13];
    const void* rel_att = d_in[14];
    const void* rel_msg = d_in[15];
    const void* rel_p  = d_in[16];

    char* p = (char*)d_ws;
    auto alloc = [&](size_t bytes) -> char* {
        char* r = p;
        p += (bytes + 255) & ~(size_t)255;
        return r;
    };
    int* flag     = (int*)alloc(sizeof(int));
    int* gcd      = (int*)alloc(sizeof(int) * NE * CB);
    int* gcs      = (int*)alloc(sizeof(int) * NE * CB);
    int* coff     = (int*)alloc(sizeof(int) * NE * (CB + 1));
    int* offs     = (int*)alloc(sizeof(int) * NE * (NN + 1));
    int* srcb     = (int*)alloc(sizeof(int) * NE * NEDGE);
    unsigned* bufd = (unsigned*)alloc(sizeof(unsigned) * NE * CB * CAP);   // 6.4 MB
    unsigned* bufs = (unsigned*)alloc(sizeof(unsigned) * NE * CB * CAP);   // 6.4 MB
    unsigned short* wTall = (unsigned short*)alloc(sizeof(short) * 18 * 16384);
    float* biasall = (float*)alloc(sizeof(float) * 18 * 128);
    float* relpf   = (float*)alloc(sizeof(float) * 16);
    float* skipf   = (float*)alloc(sizeof(float) * 4);
    float* ewsc    = (float*)alloc(sizeof(float) * NT * NN);
    float* h       = (float*)alloc(sizeof(float) * NT * NN * HID);               // 51.2 MB fp32
    unsigned short* qq = (unsigned short*)alloc(sizeof(short) * NT * NN * HID);  // fp16 (aggb aliases)
    unsigned short* kk = (unsigned short*)alloc(sizeof(short) * NT * NN * HID);  // fp16
    unsigned short* vv = (unsigned short*)alloc(sizeof(short) * NT * NN * HID);  // fp16
    unsigned short* aggb = qq;

    hipMemsetAsync(gcd, 0, sizeof(int) * NE * CB, stream);
    hipMemsetAsync(gcs, 0, sizeof(int) * NE * CB, stream);

    detect_kernel<<<1, 64, 0, stream>>>(x, flag);
    bucket1_kernel<<<NE * NCH, 256, 0, stream>>>(ei, gcd, gcs, bufd, bufs);
    cscan_kernel<<<NE, 256, 0, stream>>>(gcd, coff, offs);
    fine_dst_kernel<<<NE * CB, 256, 0, stream>>>(bufd, gcd, coff, offs, srcb);
    fine_src_kernel<<<NE * CB, 256, 0, stream>>>(bufs, gcs, ew, ewsc, flag);
    prep_w_kernel<<<18 * 64, 256, 0, stream>>>(lin_w, k_w, q_w, v_w, a_w, rel_att, rel_msg,
                                               wTall, flag);
    prep_misc_kernel<<<18, 128, 0, stream>>>(lin_b, k_b, q_b, v_b, a_b, rel_att, rel_msg,
                                             rel_p, skip, biasall, relpf, skipf, flag);

    lin_gemm<<<NT * MBLK64, 256, 0, stream>>>(x, wTall, biasall, ewsc, h, flag);

    for (int l = 0; l < NL; l++) {
        kqv_gemm<<<NT * MBLK64, 256, 0, stream>>>(h, wTall, biasall, l, kk, qq, vv);
        agg_kernel<<<NE * AGGB, 256, 0, stream>>>(qq, kk, vv, srcb, offs, relpf, l, aggb);
        outproj_gemm<<<NT * MBLK64, 256, 0, stream>>>(aggb, wTall, biasall, skipf, l, h,
                                                      (l == NL - 1) ? 1 : 0, d_out, flag);
    }
}